// Round 13
// baseline (573.269 us; speedup 1.0000x reference)
//
#include <hip/hip_runtime.h>
#include <math.h>

#define NN 50000
#define EE 800000
#define RR 8
#define SLOPE 0.2f
#define SEGS (NN * RR)            /* 400000 per-(node,relation) segments */
#define NBLK ((SEGS + 255) / 256) /* 1563 scan blocks */

__device__ __forceinline__ float leaky(float v) { return v >= 0.f ? v : SLOPE * v; }

__device__ __forceinline__ void fmacc(float4& a, const float4& v, float p) {
    a.x = fmaf(v.x, p, a.x);
    a.y = fmaf(v.y, p, a.y);
    a.z = fmaf(v.z, p, a.z);
    a.w = fmaf(v.w, p, a.w);
}

__device__ __forceinline__ void red4(float4& a, int m) {
    a.x += __shfl_xor(a.x, m);
    a.y += __shfl_xor(a.y, m);
    a.z += __shfl_xor(a.z, m);
    a.w += __shfl_xor(a.w, m);
}

// ============================ CSR build ============================
__global__ void k_count2(const int* __restrict__ dst, const int* __restrict__ et,
                         int* __restrict__ cnt2) {
    int e = blockIdx.x * 256 + threadIdx.x;
    if (e < EE) atomicAdd(&cnt2[dst[e] * RR + et[e]], 1);
}

__global__ void k_scanA(const int* __restrict__ cnt2, int* __restrict__ rp,
                        int* __restrict__ bsum) {
    __shared__ int sh[256];
    int t = threadIdx.x;
    int i = blockIdx.x * 256 + t;
    int v = (i < SEGS) ? cnt2[i] : 0;
    sh[t] = v;
    __syncthreads();
    for (int off = 1; off < 256; off <<= 1) {
        int u = (t >= off) ? sh[t - off] : 0;
        __syncthreads();
        sh[t] += u;
        __syncthreads();
    }
    if (i < SEGS) rp[i] = sh[t] - v;
    if (t == 255) bsum[blockIdx.x] = sh[255];
}

__global__ void k_scanB(int* __restrict__ bsum) {
    __shared__ int sh[256];
    int t = threadIdx.x;
    int loc[8];
    int s = 0;
#pragma unroll
    for (int i = 0; i < 8; i++) {
        int idx = t * 8 + i;
        int v = (idx < NBLK) ? bsum[idx] : 0;
        loc[i] = v;
        s += v;
    }
    sh[t] = s;
    __syncthreads();
    for (int off = 1; off < 256; off <<= 1) {
        int u = (t >= off) ? sh[t - off] : 0;
        __syncthreads();
        sh[t] += u;
        __syncthreads();
    }
    int run = sh[t] - s;
#pragma unroll
    for (int i = 0; i < 8; i++) {
        int idx = t * 8 + i;
        if (idx < NBLK) {
            int v = loc[i];
            bsum[idx] = run;
            run += v;
        }
    }
}

__global__ void k_scanC(int* __restrict__ rp, const int* __restrict__ bsum,
                        int* __restrict__ wo) {
    int i = blockIdx.x * 256 + threadIdx.x;
    if (i < SEGS) {
        int v = rp[i] + bsum[blockIdx.x];
        rp[i] = v;
        wo[i] = v;
    }
    if (i == 0) rp[SEGS] = EE;
}

// fill packed keys: srcs2[pos] = src*8 + relation (single scattered store per edge)
__global__ void k_fill(const int* __restrict__ src, const int* __restrict__ dst,
                       const int* __restrict__ et, int* __restrict__ wo,
                       int* __restrict__ srcs2) {
    int e = blockIdx.x * 256 + threadIdx.x;
    if (e >= EE) return;
    int r = et[e];
    int seg = dst[e] * RR + r;
    int pos = atomicAdd(&wo[seg], 1);
    srcs2[pos] = (src[e] << 3) | r;
}

// ==== compose extended weights: Wcat1e[64][576] (col0-63 root later), Wcat2e[128][320] ====
__global__ void k_weights(const float* __restrict__ basis1, const float* __restrict__ comp1,
                          const float* __restrict__ basis2, const float* __restrict__ comp2,
                          float* __restrict__ Wcat1e, float* __restrict__ Wcat2e) {
    int idx = blockIdx.x * 256 + threadIdx.x;
    if (idx < RR * 64 * 64) {
        int i = idx >> 9, rc = idx & 511;
        int r = rc >> 6, o = rc & 63;
        float acc = 0.f;
#pragma unroll
        for (int b = 0; b < 4; b++) acc += comp1[r * 4 + b] * basis1[b * 4096 + i * 64 + o];
        Wcat1e[i * 576 + 64 + rc] = acc;
    } else if (idx < 2 * RR * 64 * 64) {
        int j = idx - RR * 64 * 64;
        int i = j >> 8, rc = j & 255;
        int r = rc >> 5, o = rc & 31;
        float acc = 0.f;
#pragma unroll
        for (int b = 0; b < 4; b++) acc += comp2[r * 4 + b] * basis2[b * 4096 + i * 32 + o];
        Wcat2e[i * 320 + 64 + rc] = acc;
    }
}

// ==== prep: root blocks into ext weights, padded head weights, logit projections ====
__global__ void k_prep(const float* __restrict__ wg1, const float* __restrict__ wg2,
                       const float* __restrict__ root1, const float* __restrict__ root2,
                       const float* __restrict__ asrc1, const float* __restrict__ adst1,
                       const float* __restrict__ asrc2, const float* __restrict__ adst2,
                       float* __restrict__ Wcat1e, float* __restrict__ Wcat2e,
                       float* __restrict__ wg1r, float* __restrict__ Wstk,
                       float* __restrict__ U1p, float* __restrict__ U2p) {
    int idx = blockIdx.x * 256 + threadIdx.x;
    if (idx < 16384) {  // wg1r[h][k][c] (c<32 valid)
        int h = idx >> 12, kc = idx & 4095;
        int k = kc >> 6, c = kc & 63;
        wg1r[idx] = (c < 32) ? wg1[k * 128 + h * 32 + c] : 0.f;
    } else if (idx < 24576) {  // Wstk[h*32+k][c] = wg2[k][h*16+c] (c<16 valid)
        int j = idx - 16384;
        int row = j >> 6, c = j & 63;
        int h = row >> 5, k = row & 31;
        Wstk[j] = (c < 16) ? wg2[k * 64 + h * 16 + c] : 0.f;
    } else if (idx < 28672) {  // Wcat1e root block: [64][col 0-63] = root1
        int j = idx - 24576;
        int k = j >> 6, c = j & 63;
        Wcat1e[k * 576 + c] = root1[k * 64 + c];
    } else if (idx < 36864) {  // Wcat2e root block: [128][col 0-63] = root2 zero-padded
        int j = idx - 28672;
        int k = j >> 6, c = j & 63;
        Wcat2e[k * 320 + c] = (c < 32) ? root2[k * 32 + c] : 0.f;
    } else if (idx < 40960) {  // U1p[k][j]: j<4 src head j, 4<=j<8 dst head j-4, else 0
        int j0 = idx - 36864;
        int k = j0 >> 6, j = j0 & 63;
        float s = 0.f;
        if (j < 8) {
            int h = j & 3;
            const float* a = (j < 4) ? asrc1 : adst1;
            for (int c = 0; c < 32; c++) s += wg1[k * 128 + h * 32 + c] * a[h * 32 + c];
        }
        U1p[j0] = s;
    } else if (idx < 43008) {  // U2p[k][j]
        int j0 = idx - 40960;
        int k = j0 >> 6, j = j0 & 63;
        float s = 0.f;
        if (j < 8) {
            int h = j & 3;
            const float* a = (j < 4) ? asrc2 : adst2;
            for (int c = 0; c < 16; c++) s += wg2[k * 64 + h * 16 + c] * a[h * 16 + c];
        }
        U2p[j0] = s;
    }
}

// ============ tiled GEMM, swizzled Xs (2-way free banking) ============
// mbcnt>0: 1-D grid, XCD-grouped mapping — all mb blocks of a tile share block-ID mod 8
// (same XCD under round-robin dispatch) so the shared X tile hits that XCD's L2.
// mbcnt==0: plain 2-D grid (tile = blockIdx.x, mb = blockIdx.y).
// ACT=1: Y = tanh(relu(0.25*acc + bias)) (final-layer fusion).
template <int KTOT, int MV = 64, int ACT = 0>
__global__ __launch_bounds__(256) void k_gemm64(const float* __restrict__ X, int ldX, int xmb,
                                                const float* __restrict__ B, int ldB, int bmb,
                                                float* __restrict__ Y, int ldY, size_t ymb,
                                                const float* __restrict__ bias, int biasmb,
                                                int nt, int mbcnt) {
    constexpr int Kc = (KTOT < 64) ? KTOT : 64;
    constexpr int KQ = Kc / 4;
    __shared__ __align__(16) float Xs[Kc * 68];
    __shared__ __align__(16) float Ws[Kc * 68];
    const int tid = threadIdx.x;
    const int tn4 = (tid >> 4) * 4;
    const int tm4 = (tid & 15) * 4;
    int tile, mb;
    if (mbcnt) {
        int b = blockIdx.x;
        int xcd = b & 7, slot = b >> 3;
        tile = (slot / mbcnt) * 8 + xcd;
        mb = slot % mbcnt;
        if (tile >= nt) return;  // block-uniform early exit (before any barrier)
    } else {
        tile = blockIdx.x;
        mb = blockIdx.y;
    }
    const int n0 = tile * 64;
    const float* Bm = B + (size_t)mb * bmb;
    const float* Xm = X + (size_t)mb * xmb;

    float acc[4][4];
#pragma unroll
    for (int a = 0; a < 4; a++)
#pragma unroll
        for (int b = 0; b < 4; b++) acc[a][b] = 0.f;

    for (int kk = 0; kk < KTOT; kk += Kc) {
        if (kk) __syncthreads();
        for (int i = tid; i < 64 * KQ; i += 256) {
            int nl = i / KQ, kq = i % KQ;
            float4 v = make_float4(0.f, 0.f, 0.f, 0.f);
            if (n0 + nl < NN)
                v = *reinterpret_cast<const float4*>(Xm + (size_t)(n0 + nl) * ldX + kk + 4 * kq);
            int col = (nl + 4 * kq) & 63;
            Xs[(4 * kq + 0) * 68 + col] = v.x;
            Xs[(4 * kq + 1) * 68 + col] = v.y;
            Xs[(4 * kq + 2) * 68 + col] = v.z;
            Xs[(4 * kq + 3) * 68 + col] = v.w;
        }
        for (int i = tid; i < Kc * 16; i += 256) {
            int kl = i >> 4, cq = i & 15;
            float4 v = *reinterpret_cast<const float4*>(Bm + (size_t)(kk + kl) * ldB + 4 * cq);
            *reinterpret_cast<float4*>(&Ws[kl * 68 + 4 * cq]) = v;
        }
        __syncthreads();
#pragma unroll 4
        for (int k = 0; k < Kc; k++) {
            float4 xq = *reinterpret_cast<const float4*>(&Xs[k * 68 + ((tn4 + (k & ~3)) & 63)]);
            float4 wq = *reinterpret_cast<const float4*>(&Ws[k * 68 + tm4]);
            float xa[4] = {xq.x, xq.y, xq.z, xq.w};
            float wa[4] = {wq.x, wq.y, wq.z, wq.w};
#pragma unroll
            for (int a = 0; a < 4; a++)
#pragma unroll
                for (int b = 0; b < 4; b++) acc[a][b] += xa[a] * wa[b];
        }
    }
    if (MV == 64 || tm4 < MV) {
        float4 bv = make_float4(0.f, 0.f, 0.f, 0.f);
        if (bias) bv = *reinterpret_cast<const float4*>(bias + (size_t)mb * biasmb + tm4);
#pragma unroll
        for (int a = 0; a < 4; a++) {
            int n = n0 + tn4 + a;
            if (n < NN) {
                float4 v;
                if (ACT) {
                    v.x = tanhf(fmaxf(0.25f * acc[a][0] + bv.x, 0.f));
                    v.y = tanhf(fmaxf(0.25f * acc[a][1] + bv.y, 0.f));
                    v.z = tanhf(fmaxf(0.25f * acc[a][2] + bv.z, 0.f));
                    v.w = tanhf(fmaxf(0.25f * acc[a][3] + bv.w, 0.f));
                } else {
                    v = make_float4(acc[a][0] + bv.x, acc[a][1] + bv.y,
                                    acc[a][2] + bv.z, acc[a][3] + bv.w);
                }
                *reinterpret_cast<float4*>(Y + (size_t)mb * ymb + (size_t)n * ldY + tm4) = v;
            }
        }
    }
}

// ===== aggregate 1: 4 edge-groups x 16 lanes; packed keys; 1/cnt via per-wave LDS table =====
__global__ __launch_bounds__(256) void k_agg1(const int* __restrict__ rp,
                                              const int* __restrict__ srcs2,
                                              const float* __restrict__ y,
                                              const float* __restrict__ bias,
                                              float* __restrict__ x1,
                                              int r0, int nrel, int final_pass) {
    __shared__ float sh_inv[4][8];
    int wid = threadIdx.x >> 6, lane = threadIdx.x & 63;
    int n = blockIdx.x * 4 + wid;
    int rpv = (lane <= 8) ? rp[n * RR + lane] : 0;
    int nxt = __shfl(rpv, (lane + 1) & 63);
    if (lane < 8) sh_inv[wid][lane] = 1.f / (float)((nxt - rpv) > 0 ? (nxt - rpv) : 1);
    int q = lane & 15;
    int beg = rp[n * RR + r0], end = rp[n * RR + r0 + nrel];
    float4 acc = make_float4(0.f, 0.f, 0.f, 0.f);
    int k = beg + (lane >> 4);
    for (; k + 4 < end; k += 8) {
        int key0 = srcs2[k], key1 = srcs2[k + 4];
        int s0 = key0 >> 3, s1 = key1 >> 3;
        float e0 = sh_inv[wid][key0 & 7], e1 = sh_inv[wid][key1 & 7];
        int ra = (key0 & 7) - r0, rb = (key1 & 7) - r0;
        float4 v0 = *(const float4*)(y + ((size_t)ra * NN + s0) * 64 + q * 4);
        float4 v1 = *(const float4*)(y + ((size_t)rb * NN + s1) * 64 + q * 4);
        fmacc(acc, v0, e0);
        fmacc(acc, v1, e1);
    }
    if (k < end) {
        int key0 = srcs2[k];
        int s0 = key0 >> 3;
        int ra = (key0 & 7) - r0;
        float4 v0 = *(const float4*)(y + ((size_t)ra * NN + s0) * 64 + q * 4);
        fmacc(acc, v0, sh_inv[wid][key0 & 7]);
    }
    red4(acc, 16);
    red4(acc, 32);
    if (lane < 16) {
        float4 prev = *(const float4*)(x1 + (size_t)n * 64 + q * 4);
        float4 v = make_float4(prev.x + acc.x, prev.y + acc.y, prev.z + acc.z, prev.w + acc.w);
        if (final_pass) {
            float4 b = *(const float4*)(bias + q * 4);
            v.x = fmaxf(v.x + b.x, 0.f);
            v.y = fmaxf(v.y + b.y, 0.f);
            v.z = fmaxf(v.z + b.z, 0.f);
            v.w = fmaxf(v.w + b.w, 0.f);
        }
        *(float4*)(x1 + (size_t)n * 64 + q * 4) = v;
    }
}

// ===== aggregate 2: 8 edge-groups x 8 lanes; single pass; x3 stride 64 (cols 32-63 pad) =====
__global__ __launch_bounds__(256) void k_agg2(const int* __restrict__ rp,
                                              const int* __restrict__ srcs2,
                                              const float* __restrict__ y,
                                              const float* __restrict__ bias,
                                              float* __restrict__ x3) {
    __shared__ float sh_inv[4][8];
    int wid = threadIdx.x >> 6, lane = threadIdx.x & 63;
    int n = blockIdx.x * 4 + wid;
    int rpv = (lane <= 8) ? rp[n * RR + lane] : 0;
    int nxt = __shfl(rpv, (lane + 1) & 63);
    if (lane < 8) sh_inv[wid][lane] = 1.f / (float)((nxt - rpv) > 0 ? (nxt - rpv) : 1);
    int q = lane & 7;
    int beg = rp[n * RR], end = rp[n * RR + RR];
    float4 acc = make_float4(0.f, 0.f, 0.f, 0.f);
    int k = beg + (lane >> 3);
    for (; k + 8 < end; k += 16) {
        int key0 = srcs2[k], key1 = srcs2[k + 8];
        int s0 = key0 >> 3, s1 = key1 >> 3;
        int g0 = key0 & 7, g1 = key1 & 7;
        float e0 = sh_inv[wid][g0], e1 = sh_inv[wid][g1];
        float4 v0 = *(const float4*)(y + ((size_t)(g0 >> 1) * NN + s0) * 64 + (g0 & 1) * 32 + q * 4);
        float4 v1 = *(const float4*)(y + ((size_t)(g1 >> 1) * NN + s1) * 64 + (g1 & 1) * 32 + q * 4);
        fmacc(acc, v0, e0);
        fmacc(acc, v1, e1);
    }
    if (k < end) {
        int key0 = srcs2[k];
        int s0 = key0 >> 3;
        int g0 = key0 & 7;
        float4 v0 = *(const float4*)(y + ((size_t)(g0 >> 1) * NN + s0) * 64 + (g0 & 1) * 32 + q * 4);
        fmacc(acc, v0, sh_inv[wid][g0]);
    }
    red4(acc, 8);
    red4(acc, 16);
    red4(acc, 32);
    if (lane < 8) {
        float4 prev = *(const float4*)(x3 + (size_t)n * 64 + q * 4);
        float4 b = *(const float4*)(bias + q * 4);
        float4 v;
        v.x = fmaxf(prev.x + acc.x + b.x, 0.f);
        v.y = fmaxf(prev.y + acc.y + b.y, 0.f);
        v.z = fmaxf(prev.z + acc.z + b.z, 0.f);
        v.w = fmaxf(prev.w + acc.w + b.w, 0.f);
        *(float4*)(x3 + (size_t)n * 64 + q * 4) = v;
    }
}

// ===== fused GAT aggregation in input space; alds[n][8] = (als[0..3], ald[0..3]) =====
template <int F, int LDX = F>
__global__ __launch_bounds__(256) void k_gatx(const int* __restrict__ rp,
                                              const int* __restrict__ srcs2,
                                              const float* __restrict__ alds,
                                              const float* __restrict__ X,
                                              float* __restrict__ msg) {
    constexpr int G = F / 4;    // lanes per edge-group (16 or 8)
    constexpr int NG = 64 / G;  // groups per wave (4 or 8)
    int wid = threadIdx.x >> 6, lane = threadIdx.x & 63;
    int n = blockIdx.x * 4 + wid;
    if (n >= NN) return;
    int g = lane / G, q = lane % G;
    float4 ald4 = *(const float4*)(alds + n * 8 + 4);
    float4 acc0 = make_float4(0.f, 0.f, 0.f, 0.f);
    float4 acc1 = acc0, acc2 = acc0, acc3 = acc0;
    float4 z = make_float4(0.f, 0.f, 0.f, 0.f);
    if (g == 0) {  // self loop
        float4 a4 = *(const float4*)(alds + n * 8);
        float4 xv = *(const float4*)(X + (size_t)n * LDX + q * 4);
        float p0 = __expf(leaky(a4.x + ald4.x));
        float p1 = __expf(leaky(a4.y + ald4.y));
        float p2 = __expf(leaky(a4.z + ald4.z));
        float p3 = __expf(leaky(a4.w + ald4.w));
        z = make_float4(p0, p1, p2, p3);
        fmacc(acc0, xv, p0);
        fmacc(acc1, xv, p1);
        fmacc(acc2, xv, p2);
        fmacc(acc3, xv, p3);
    }
    int beg = rp[n * RR], end = rp[n * RR + RR];
    int k = beg + g;
    for (; k + NG < end; k += 2 * NG) {
        int s0 = srcs2[k] >> 3, s1 = srcs2[k + NG] >> 3;
        float4 a0 = *(const float4*)(alds + s0 * 8);
        float4 a1 = *(const float4*)(alds + s1 * 8);
        float4 x0 = *(const float4*)(X + (size_t)s0 * LDX + q * 4);
        float4 x1v = *(const float4*)(X + (size_t)s1 * LDX + q * 4);
        float p00 = __expf(leaky(a0.x + ald4.x)), p01 = __expf(leaky(a0.y + ald4.y));
        float p02 = __expf(leaky(a0.z + ald4.z)), p03 = __expf(leaky(a0.w + ald4.w));
        float p10 = __expf(leaky(a1.x + ald4.x)), p11 = __expf(leaky(a1.y + ald4.y));
        float p12 = __expf(leaky(a1.z + ald4.z)), p13 = __expf(leaky(a1.w + ald4.w));
        z.x += p00 + p10;
        z.y += p01 + p11;
        z.z += p02 + p12;
        z.w += p03 + p13;
        fmacc(acc0, x0, p00);
        fmacc(acc1, x0, p01);
        fmacc(acc2, x0, p02);
        fmacc(acc3, x0, p03);
        fmacc(acc0, x1v, p10);
        fmacc(acc1, x1v, p11);
        fmacc(acc2, x1v, p12);
        fmacc(acc3, x1v, p13);
    }
    if (k < end) {
        int s0 = srcs2[k] >> 3;
        float4 a0 = *(const float4*)(alds + s0 * 8);
        float4 x0 = *(const float4*)(X + (size_t)s0 * LDX + q * 4);
        float p00 = __expf(leaky(a0.x + ald4.x)), p01 = __expf(leaky(a0.y + ald4.y));
        float p02 = __expf(leaky(a0.z + ald4.z)), p03 = __expf(leaky(a0.w + ald4.w));
        z.x += p00;
        z.y += p01;
        z.z += p02;
        z.w += p03;
        fmacc(acc0, x0, p00);
        fmacc(acc1, x0, p01);
        fmacc(acc2, x0, p02);
        fmacc(acc3, x0, p03);
    }
#pragma unroll
    for (int m = G; m < 64; m <<= 1) {
        red4(acc0, m);
        red4(acc1, m);
        red4(acc2, m);
        red4(acc3, m);
        red4(z, m);
    }
    if (g == 0) {
        float4 iz = make_float4(1.f / z.x, 1.f / z.y, 1.f / z.z, 1.f / z.w);
        float* mp = msg + (size_t)n * 4 * F + q * 4;
        *(float4*)(mp + 0 * F) = make_float4(acc0.x * iz.x, acc0.y * iz.x, acc0.z * iz.x, acc0.w * iz.x);
        *(float4*)(mp + 1 * F) = make_float4(acc1.x * iz.y, acc1.y * iz.y, acc1.z * iz.y, acc1.w * iz.y);
        *(float4*)(mp + 2 * F) = make_float4(acc2.x * iz.z, acc2.y * iz.z, acc2.z * iz.z, acc2.w * iz.z);
        *(float4*)(mp + 3 * F) = make_float4(acc3.x * iz.w, acc3.y * iz.w, acc3.z * iz.w, acc3.w * iz.w);
    }
}

extern "C" void kernel_launch(void* const* d_in, const int* in_sizes, int n_in,
                              void* d_out, int out_size, void* d_ws, size_t ws_size,
                              hipStream_t stream) {
    const float* x      = (const float*)d_in[0];
    const int*   ei     = (const int*)d_in[1];
    const int*   et     = (const int*)d_in[2];
    const float* basis1 = (const float*)d_in[3];
    const float* comp1  = (const float*)d_in[4];
    const float* root1  = (const float*)d_in[5];
    const float* brg1   = (const float*)d_in[6];
    const float* wg1    = (const float*)d_in[7];
    const float* asrc1  = (const float*)d_in[8];
    const float* adst1  = (const float*)d_in[9];
    const float* bg1    = (const float*)d_in[10];
    const float* basis2 = (const float*)d_in[11];
    const float* comp2  = (const float*)d_in[12];
    const float* root2  = (const float*)d_in[13];
    const float* brg2   = (const float*)d_in[14];
    const float* wg2    = (const float*)d_in[15];
    const float* asrc2  = (const float*)d_in[16];
    const float* adst2  = (const float*)d_in[17];
    const float* bg2    = (const float*)d_in[18];
    const int* src = ei;
    const int* dst = ei + EE;
    float* out = (float*)d_out;

    // ---- int region ----
    int* wsi = (int*)d_ws;
    size_t ioff = 0;
    auto ialloc = [&](size_t n) { int* p = wsi + ioff; ioff += (n + 3) & ~(size_t)3; return p; };
    int* cnt2 = ialloc(SEGS);  // reused as fill cursors (wo)
    int* rp   = ialloc(SEGS + 1);
    int* bsum = ialloc(2048);
    int* srcs2 = ialloc(EE);
    int* wo = cnt2;
    // ---- float region ----
    float* wsf = (float*)(wsi + ioff);
    size_t total_f = (ws_size - ioff * sizeof(int)) / sizeof(float);
    // P region: [x1/x3 : NN*64][ybuf : NN*256] contiguous so fused gemm writes mb*NN*64
    size_t P_f = (size_t)NN * 64 + (size_t)4 * NN * 64;
    size_t need_f = P_f + (size_t)NN * 128
                  + 36864 + 40960 + 16384 + 8192 + 4096 + 2048
                  + (size_t)NN * 8 + 64;
    if (total_f < need_f) return;  // loud fail: output stays zero
    size_t foff = 0;
    auto falloc = [&](size_t n) { float* p = wsf + foff; foff += (n + 3) & ~(size_t)3; return p; };
    float* P      = falloc(P_f);             // x1/x3 | ybuf
    float* x2     = falloc((size_t)NN * 128);
    float* Wcat1e = falloc(36864);           // [64][576]: root1 | W_r r=0..7
    float* Wcat2e = falloc(40960);           // [128][320]: root2(pad) | W_r pairs
    float* wg1r   = falloc(16384);
    float* Wstk   = falloc(8192);
    float* U1p    = falloc(4096);
    float* U2p    = falloc(2048);
    float* alds   = falloc((size_t)NN * 8);
    float* x1   = P;
    float* ybuf = P + (size_t)NN * 64;
    float* msg1 = ybuf;  // [n][4][64]
    float* msg2 = ybuf;  // [n][4][32]
    float* x3 = x1;      // stride 64, cols 32-63 zero-pad

    const int EB = (EE + 255) / 256;
    const int NB4 = (NN + 3) / 4;   // NN % 4 == 0 -> exact
    const int NT = (NN + 63) / 64;  // 782 node tiles
    const int NT8 = ((NT + 7) / 8) * 8;  // 784: XCD-swizzle grid rounding

    // ---- CSR build ----
    hipMemsetAsync(cnt2, 0, SEGS * sizeof(int), stream);
    k_count2<<<EB, 256, 0, stream>>>(dst, et, cnt2);
    k_scanA<<<NBLK, 256, 0, stream>>>(cnt2, rp, bsum);
    k_scanB<<<1, 256, 0, stream>>>(bsum);
    k_scanC<<<NBLK, 256, 0, stream>>>(rp, bsum, wo);
    k_fill<<<EB, 256, 0, stream>>>(src, dst, et, wo, srcs2);
    k_weights<<<(2 * RR * 4096) / 256, 256, 0, stream>>>(basis1, comp1, basis2, comp2, Wcat1e, Wcat2e);
    k_prep<<<(43008 + 255) / 256, 256, 0, stream>>>(
        wg1, wg2, root1, root2, asrc1, adst1, asrc2, adst2, Wcat1e, Wcat2e, wg1r, Wstk, U1p, U2p);

    // ---- layer 1: RGCN(64->64)+relu; XCD-swizzled fused transform (root + rel 0-3), then 4-7 ----
    k_gemm64<64><<<NT8 * 5, 256, 0, stream>>>(x, 64, 0, Wcat1e, 576, 64,
                                              P, 64, (size_t)NN * 64, nullptr, 0, NT, 5);
    k_agg1<<<NB4, 256, 0, stream>>>(rp, srcs2, ybuf, brg1, x1, 0, 4, 0);
    k_gemm64<64><<<NT8 * 4, 256, 0, stream>>>(x, 64, 0, Wcat1e + 320, 576, 64,
                                              ybuf, 64, (size_t)NN * 64, nullptr, 0, NT, 4);
    k_agg1<<<NB4, 256, 0, stream>>>(rp, srcs2, ybuf, brg1, x1, 4, 4, 1);

    // ---- layer 2: GAT(64 -> 4x32 concat), aggregated in input space ----
    k_gemm64<64, 8><<<dim3(NT, 1), 256, 0, stream>>>(x1, 64, 0, U1p, 64, 0, alds, 8, 0,
                                                     nullptr, 0, NT, 0);
    k_gatx<64><<<NB4, 256, 0, stream>>>(rp, srcs2, alds, x1, msg1);
    k_gemm64<64, 32><<<dim3(NT, 4), 256, 0, stream>>>(msg1, 256, 64, wg1r, 64, 4096,
                                                      x2, 128, 32, bg1, 32, NT, 0);

    // ---- layer 3: RGCN(128->32)+relu; XCD-swizzled fused transform (root + 8 rel) ----
    k_gemm64<128><<<NT8 * 5, 256, 0, stream>>>(x2, 128, 0, Wcat2e, 320, 64,
                                               P, 64, (size_t)NN * 64, nullptr, 0, NT, 5);
    k_agg2<<<NB4, 256, 0, stream>>>(rp, srcs2, ybuf, brg2, x3);

    // ---- layer 4: GAT(32 -> 4x16, mean heads) + relu + tanh (fused into stack gemm) ----
    k_gemm64<32, 8><<<dim3(NT, 1), 256, 0, stream>>>(x3, 64, 0, U2p, 64, 0, alds, 8, 0,
                                                     nullptr, 0, NT, 0);
    k_gatx<32, 64><<<NB4, 256, 0, stream>>>(rp, srcs2, alds, x3, msg2);
    k_gemm64<128, 16, 1><<<dim3(NT, 1), 256, 0, stream>>>(msg2, 128, 0, Wstk, 64, 0,
                                                          out, 16, 0, bg2, 0, NT, 0);
}

// Round 14
// 572.293 us; speedup vs baseline: 1.0017x; 1.0017x over previous
//
#include <hip/hip_runtime.h>
#include <math.h>

#define NN 50000
#define EE 800000
#define RR 8
#define SLOPE 0.2f
#define SEGS (NN * RR)            /* 400000 per-(node,relation) segments */
#define NBLK ((SEGS + 255) / 256) /* 1563 scan blocks */

__device__ __forceinline__ float leaky(float v) { return v >= 0.f ? v : SLOPE * v; }

__device__ __forceinline__ void fmacc(float4& a, const float4& v, float p) {
    a.x = fmaf(v.x, p, a.x);
    a.y = fmaf(v.y, p, a.y);
    a.z = fmaf(v.z, p, a.z);
    a.w = fmaf(v.w, p, a.w);
}

__device__ __forceinline__ void red4(float4& a, int m) {
    a.x += __shfl_xor(a.x, m);
    a.y += __shfl_xor(a.y, m);
    a.z += __shfl_xor(a.z, m);
    a.w += __shfl_xor(a.w, m);
}

// ============================ CSR build ============================
__global__ void k_count2(const int* __restrict__ dst, const int* __restrict__ et,
                         int* __restrict__ cnt2) {
    int e = blockIdx.x * 256 + threadIdx.x;
    if (e < EE) atomicAdd(&cnt2[dst[e] * RR + et[e]], 1);
}

__global__ void k_scanA(const int* __restrict__ cnt2, int* __restrict__ rp,
                        int* __restrict__ bsum) {
    __shared__ int sh[256];
    int t = threadIdx.x;
    int i = blockIdx.x * 256 + t;
    int v = (i < SEGS) ? cnt2[i] : 0;
    sh[t] = v;
    __syncthreads();
    for (int off = 1; off < 256; off <<= 1) {
        int u = (t >= off) ? sh[t - off] : 0;
        __syncthreads();
        sh[t] += u;
        __syncthreads();
    }
    if (i < SEGS) rp[i] = sh[t] - v;
    if (t == 255) bsum[blockIdx.x] = sh[255];
}

__global__ void k_scanB(int* __restrict__ bsum) {
    __shared__ int sh[256];
    int t = threadIdx.x;
    int loc[8];
    int s = 0;
#pragma unroll
    for (int i = 0; i < 8; i++) {
        int idx = t * 8 + i;
        int v = (idx < NBLK) ? bsum[idx] : 0;
        loc[i] = v;
        s += v;
    }
    sh[t] = s;
    __syncthreads();
    for (int off = 1; off < 256; off <<= 1) {
        int u = (t >= off) ? sh[t - off] : 0;
        __syncthreads();
        sh[t] += u;
        __syncthreads();
    }
    int run = sh[t] - s;
#pragma unroll
    for (int i = 0; i < 8; i++) {
        int idx = t * 8 + i;
        if (idx < NBLK) {
            int v = loc[i];
            bsum[idx] = run;
            run += v;
        }
    }
}

__global__ void k_scanC(int* __restrict__ rp, const int* __restrict__ bsum,
                        int* __restrict__ wo) {
    int i = blockIdx.x * 256 + threadIdx.x;
    if (i < SEGS) {
        int v = rp[i] + bsum[blockIdx.x];
        rp[i] = v;
        wo[i] = v;
    }
    if (i == 0) rp[SEGS] = EE;
}

// fill packed keys: srcs2[pos] = src*8 + relation (single scattered store per edge)
__global__ void k_fill(const int* __restrict__ src, const int* __restrict__ dst,
                       const int* __restrict__ et, int* __restrict__ wo,
                       int* __restrict__ srcs2) {
    int e = blockIdx.x * 256 + threadIdx.x;
    if (e >= EE) return;
    int r = et[e];
    int seg = dst[e] * RR + r;
    int pos = atomicAdd(&wo[seg], 1);
    srcs2[pos] = (src[e] << 3) | r;
}

// ==== compose extended weights: Wcat1e[64][576] (col0-63 root later), Wcat2e[128][320] ====
__global__ void k_weights(const float* __restrict__ basis1, const float* __restrict__ comp1,
                          const float* __restrict__ basis2, const float* __restrict__ comp2,
                          float* __restrict__ Wcat1e, float* __restrict__ Wcat2e) {
    int idx = blockIdx.x * 256 + threadIdx.x;
    if (idx < RR * 64 * 64) {
        int i = idx >> 9, rc = idx & 511;
        int r = rc >> 6, o = rc & 63;
        float acc = 0.f;
#pragma unroll
        for (int b = 0; b < 4; b++) acc += comp1[r * 4 + b] * basis1[b * 4096 + i * 64 + o];
        Wcat1e[i * 576 + 64 + rc] = acc;
    } else if (idx < 2 * RR * 64 * 64) {
        int j = idx - RR * 64 * 64;
        int i = j >> 8, rc = j & 255;
        int r = rc >> 5, o = rc & 31;
        float acc = 0.f;
#pragma unroll
        for (int b = 0; b < 4; b++) acc += comp2[r * 4 + b] * basis2[b * 4096 + i * 32 + o];
        Wcat2e[i * 320 + 64 + rc] = acc;
    }
}

// ==== prep: root blocks into ext weights, padded head weights, logit projections ====
__global__ void k_prep(const float* __restrict__ wg1, const float* __restrict__ wg2,
                       const float* __restrict__ root1, const float* __restrict__ root2,
                       const float* __restrict__ asrc1, const float* __restrict__ adst1,
                       const float* __restrict__ asrc2, const float* __restrict__ adst2,
                       float* __restrict__ Wcat1e, float* __restrict__ Wcat2e,
                       float* __restrict__ wg1r, float* __restrict__ Wstk,
                       float* __restrict__ U1p, float* __restrict__ U2p) {
    int idx = blockIdx.x * 256 + threadIdx.x;
    if (idx < 16384) {  // wg1r[h][k][c] (c<32 valid)
        int h = idx >> 12, kc = idx & 4095;
        int k = kc >> 6, c = kc & 63;
        wg1r[idx] = (c < 32) ? wg1[k * 128 + h * 32 + c] : 0.f;
    } else if (idx < 24576) {  // Wstk[h*32+k][c] = wg2[k][h*16+c] (c<16 valid)
        int j = idx - 16384;
        int row = j >> 6, c = j & 63;
        int h = row >> 5, k = row & 31;
        Wstk[j] = (c < 16) ? wg2[k * 64 + h * 16 + c] : 0.f;
    } else if (idx < 28672) {  // Wcat1e root block: [64][col 0-63] = root1
        int j = idx - 24576;
        int k = j >> 6, c = j & 63;
        Wcat1e[k * 576 + c] = root1[k * 64 + c];
    } else if (idx < 36864) {  // Wcat2e root block: [128][col 0-63] = root2 zero-padded
        int j = idx - 28672;
        int k = j >> 6, c = j & 63;
        Wcat2e[k * 320 + c] = (c < 32) ? root2[k * 32 + c] : 0.f;
    } else if (idx < 40960) {  // U1p[k][j]: j<4 src head j, 4<=j<8 dst head j-4, else 0
        int j0 = idx - 36864;
        int k = j0 >> 6, j = j0 & 63;
        float s = 0.f;
        if (j < 8) {
            int h = j & 3;
            const float* a = (j < 4) ? asrc1 : adst1;
            for (int c = 0; c < 32; c++) s += wg1[k * 128 + h * 32 + c] * a[h * 32 + c];
        }
        U1p[j0] = s;
    } else if (idx < 43008) {  // U2p[k][j]
        int j0 = idx - 40960;
        int k = j0 >> 6, j = j0 & 63;
        float s = 0.f;
        if (j < 8) {
            int h = j & 3;
            const float* a = (j < 4) ? asrc2 : adst2;
            for (int c = 0; c < 16; c++) s += wg2[k * 64 + h * 16 + c] * a[h * 16 + c];
        }
        U2p[j0] = s;
    }
}

// ============ big tiled GEMM: 128 nodes x 64 cols per block, 8x4 per thread ============
// Xs transposed+swizzled (col' = (node + (k&~3)) & 127); mbcnt>0 -> XCD-grouped 1-D grid.
template <int KTOT, int MV = 64>
__global__ __launch_bounds__(256) void k_gemm128(const float* __restrict__ X, int ldX, int xmb,
                                                 const float* __restrict__ B, int ldB, int bmb,
                                                 float* __restrict__ Y, int ldY, size_t ymb,
                                                 const float* __restrict__ bias, int biasmb,
                                                 int nt, int mbcnt) {
    constexpr int Kc = (KTOT < 64) ? KTOT : 64;
    constexpr int KQ = Kc / 4;
    __shared__ __align__(16) float Xs[Kc * 136];
    __shared__ __align__(16) float Ws[Kc * 68];
    const int tid = threadIdx.x;
    const int tn8 = (tid >> 4) * 8;
    const int tm4 = (tid & 15) * 4;
    int tile, mb;
    if (mbcnt) {
        int b = blockIdx.x;
        int xcd = b & 7, slot = b >> 3;
        tile = (slot / mbcnt) * 8 + xcd;
        mb = slot % mbcnt;
        if (tile >= nt) return;  // block-uniform early exit (before any barrier)
    } else {
        tile = blockIdx.x;
        mb = blockIdx.y;
    }
    const int n0 = tile * 128;
    const float* Bm = B + (size_t)mb * bmb;
    const float* Xm = X + (size_t)mb * xmb;

    float acc[8][4];
#pragma unroll
    for (int a = 0; a < 8; a++)
#pragma unroll
        for (int b = 0; b < 4; b++) acc[a][b] = 0.f;

    for (int kk = 0; kk < KTOT; kk += Kc) {
        if (kk) __syncthreads();
        // stage 128-node X tile transposed + swizzled
        for (int i = tid; i < 128 * KQ; i += 256) {
            int nl = i / KQ, kq = i % KQ;
            float4 v = make_float4(0.f, 0.f, 0.f, 0.f);
            if (n0 + nl < NN)
                v = *reinterpret_cast<const float4*>(Xm + (size_t)(n0 + nl) * ldX + kk + 4 * kq);
            int col = (nl + 4 * kq) & 127;
            Xs[(4 * kq + 0) * 136 + col] = v.x;
            Xs[(4 * kq + 1) * 136 + col] = v.y;
            Xs[(4 * kq + 2) * 136 + col] = v.z;
            Xs[(4 * kq + 3) * 136 + col] = v.w;
        }
        for (int i = tid; i < Kc * 16; i += 256) {
            int kl = i >> 4, cq = i & 15;
            float4 v = *reinterpret_cast<const float4*>(Bm + (size_t)(kk + kl) * ldB + 4 * cq);
            *reinterpret_cast<float4*>(&Ws[kl * 68 + 4 * cq]) = v;
        }
        __syncthreads();
#pragma unroll 4
        for (int k = 0; k < Kc; k++) {
            int base = k * 136 + (k & ~3);
            float4 xq0 = *reinterpret_cast<const float4*>(&Xs[k * 136 + ((tn8 + (k & ~3)) & 127)]);
            float4 xq1 = *reinterpret_cast<const float4*>(&Xs[k * 136 + ((tn8 + 4 + (k & ~3)) & 127)]);
            float4 wq = *reinterpret_cast<const float4*>(&Ws[k * 68 + tm4]);
            (void)base;
            float xa[8] = {xq0.x, xq0.y, xq0.z, xq0.w, xq1.x, xq1.y, xq1.z, xq1.w};
            float wa[4] = {wq.x, wq.y, wq.z, wq.w};
#pragma unroll
            for (int a = 0; a < 8; a++)
#pragma unroll
                for (int b = 0; b < 4; b++) acc[a][b] += xa[a] * wa[b];
        }
    }
    if (MV == 64 || tm4 < MV) {
        float4 bv = make_float4(0.f, 0.f, 0.f, 0.f);
        if (bias) bv = *reinterpret_cast<const float4*>(bias + (size_t)mb * biasmb + tm4);
#pragma unroll
        for (int a = 0; a < 8; a++) {
            int n = n0 + tn8 + a;
            if (n < NN) {
                float4 v = make_float4(acc[a][0] + bv.x, acc[a][1] + bv.y,
                                       acc[a][2] + bv.z, acc[a][3] + bv.w);
                *reinterpret_cast<float4*>(Y + (size_t)mb * ymb + (size_t)n * ldY + tm4) = v;
            }
        }
    }
}

// ============ small tiled GEMM (64x64 tile, 4x4/thread) — proven R12 kernel ============
template <int KTOT, int MV = 64, int ACT = 0>
__global__ __launch_bounds__(256) void k_gemm64(const float* __restrict__ X, int ldX, int xmb,
                                                const float* __restrict__ B, int ldB, int bmb,
                                                float* __restrict__ Y, int ldY, size_t ymb,
                                                const float* __restrict__ bias, int biasmb,
                                                int nt, int mbcnt) {
    constexpr int Kc = (KTOT < 64) ? KTOT : 64;
    constexpr int KQ = Kc / 4;
    __shared__ __align__(16) float Xs[Kc * 68];
    __shared__ __align__(16) float Ws[Kc * 68];
    const int tid = threadIdx.x;
    const int tn4 = (tid >> 4) * 4;
    const int tm4 = (tid & 15) * 4;
    int tile, mb;
    if (mbcnt) {
        int b = blockIdx.x;
        int xcd = b & 7, slot = b >> 3;
        tile = (slot / mbcnt) * 8 + xcd;
        mb = slot % mbcnt;
        if (tile >= nt) return;
    } else {
        tile = blockIdx.x;
        mb = blockIdx.y;
    }
    const int n0 = tile * 64;
    const float* Bm = B + (size_t)mb * bmb;
    const float* Xm = X + (size_t)mb * xmb;

    float acc[4][4];
#pragma unroll
    for (int a = 0; a < 4; a++)
#pragma unroll
        for (int b = 0; b < 4; b++) acc[a][b] = 0.f;

    for (int kk = 0; kk < KTOT; kk += Kc) {
        if (kk) __syncthreads();
        for (int i = tid; i < 64 * KQ; i += 256) {
            int nl = i / KQ, kq = i % KQ;
            float4 v = make_float4(0.f, 0.f, 0.f, 0.f);
            if (n0 + nl < NN)
                v = *reinterpret_cast<const float4*>(Xm + (size_t)(n0 + nl) * ldX + kk + 4 * kq);
            int col = (nl + 4 * kq) & 63;
            Xs[(4 * kq + 0) * 68 + col] = v.x;
            Xs[(4 * kq + 1) * 68 + col] = v.y;
            Xs[(4 * kq + 2) * 68 + col] = v.z;
            Xs[(4 * kq + 3) * 68 + col] = v.w;
        }
        for (int i = tid; i < Kc * 16; i += 256) {
            int kl = i >> 4, cq = i & 15;
            float4 v = *reinterpret_cast<const float4*>(Bm + (size_t)(kk + kl) * ldB + 4 * cq);
            *reinterpret_cast<float4*>(&Ws[kl * 68 + 4 * cq]) = v;
        }
        __syncthreads();
#pragma unroll 4
        for (int k = 0; k < Kc; k++) {
            float4 xq = *reinterpret_cast<const float4*>(&Xs[k * 68 + ((tn4 + (k & ~3)) & 63)]);
            float4 wq = *reinterpret_cast<const float4*>(&Ws[k * 68 + tm4]);
            float xa[4] = {xq.x, xq.y, xq.z, xq.w};
            float wa[4] = {wq.x, wq.y, wq.z, wq.w};
#pragma unroll
            for (int a = 0; a < 4; a++)
#pragma unroll
                for (int b = 0; b < 4; b++) acc[a][b] += xa[a] * wa[b];
        }
    }
    if (MV == 64 || tm4 < MV) {
        float4 bv = make_float4(0.f, 0.f, 0.f, 0.f);
        if (bias) bv = *reinterpret_cast<const float4*>(bias + (size_t)mb * biasmb + tm4);
#pragma unroll
        for (int a = 0; a < 4; a++) {
            int n = n0 + tn4 + a;
            if (n < NN) {
                float4 v;
                if (ACT) {
                    v.x = tanhf(fmaxf(0.25f * acc[a][0] + bv.x, 0.f));
                    v.y = tanhf(fmaxf(0.25f * acc[a][1] + bv.y, 0.f));
                    v.z = tanhf(fmaxf(0.25f * acc[a][2] + bv.z, 0.f));
                    v.w = tanhf(fmaxf(0.25f * acc[a][3] + bv.w, 0.f));
                } else {
                    v = make_float4(acc[a][0] + bv.x, acc[a][1] + bv.y,
                                    acc[a][2] + bv.z, acc[a][3] + bv.w);
                }
                *reinterpret_cast<float4*>(Y + (size_t)mb * ymb + (size_t)n * ldY + tm4) = v;
            }
        }
    }
}

// ===== aggregate 1: 4 edge-groups x 16 lanes; packed keys; 1/cnt via per-wave LDS table =====
__global__ __launch_bounds__(256) void k_agg1(const int* __restrict__ rp,
                                              const int* __restrict__ srcs2,
                                              const float* __restrict__ y,
                                              const float* __restrict__ bias,
                                              float* __restrict__ x1,
                                              int r0, int nrel, int final_pass) {
    __shared__ float sh_inv[4][8];
    int wid = threadIdx.x >> 6, lane = threadIdx.x & 63;
    int n = blockIdx.x * 4 + wid;
    int rpv = (lane <= 8) ? rp[n * RR + lane] : 0;
    int nxt = __shfl(rpv, (lane + 1) & 63);
    if (lane < 8) sh_inv[wid][lane] = 1.f / (float)((nxt - rpv) > 0 ? (nxt - rpv) : 1);
    int q = lane & 15;
    int beg = rp[n * RR + r0], end = rp[n * RR + r0 + nrel];
    float4 acc = make_float4(0.f, 0.f, 0.f, 0.f);
    int k = beg + (lane >> 4);
    for (; k + 4 < end; k += 8) {
        int key0 = srcs2[k], key1 = srcs2[k + 4];
        int s0 = key0 >> 3, s1 = key1 >> 3;
        float e0 = sh_inv[wid][key0 & 7], e1 = sh_inv[wid][key1 & 7];
        int ra = (key0 & 7) - r0, rb = (key1 & 7) - r0;
        float4 v0 = *(const float4*)(y + ((size_t)ra * NN + s0) * 64 + q * 4);
        float4 v1 = *(const float4*)(y + ((size_t)rb * NN + s1) * 64 + q * 4);
        fmacc(acc, v0, e0);
        fmacc(acc, v1, e1);
    }
    if (k < end) {
        int key0 = srcs2[k];
        int s0 = key0 >> 3;
        int ra = (key0 & 7) - r0;
        float4 v0 = *(const float4*)(y + ((size_t)ra * NN + s0) * 64 + q * 4);
        fmacc(acc, v0, sh_inv[wid][key0 & 7]);
    }
    red4(acc, 16);
    red4(acc, 32);
    if (lane < 16) {
        float4 prev = *(const float4*)(x1 + (size_t)n * 64 + q * 4);
        float4 v = make_float4(prev.x + acc.x, prev.y + acc.y, prev.z + acc.z, prev.w + acc.w);
        if (final_pass) {
            float4 b = *(const float4*)(bias + q * 4);
            v.x = fmaxf(v.x + b.x, 0.f);
            v.y = fmaxf(v.y + b.y, 0.f);
            v.z = fmaxf(v.z + b.z, 0.f);
            v.w = fmaxf(v.w + b.w, 0.f);
        }
        *(float4*)(x1 + (size_t)n * 64 + q * 4) = v;
    }
}

// ===== aggregate 2: 8 edge-groups x 8 lanes; single pass; x3 stride 64 (cols 32-63 pad) =====
__global__ __launch_bounds__(256) void k_agg2(const int* __restrict__ rp,
                                              const int* __restrict__ srcs2,
                                              const float* __restrict__ y,
                                              const float* __restrict__ bias,
                                              float* __restrict__ x3) {
    __shared__ float sh_inv[4][8];
    int wid = threadIdx.x >> 6, lane = threadIdx.x & 63;
    int n = blockIdx.x * 4 + wid;
    int rpv = (lane <= 8) ? rp[n * RR + lane] : 0;
    int nxt = __shfl(rpv, (lane + 1) & 63);
    if (lane < 8) sh_inv[wid][lane] = 1.f / (float)((nxt - rpv) > 0 ? (nxt - rpv) : 1);
    int q = lane & 7;
    int beg = rp[n * RR], end = rp[n * RR + RR];
    float4 acc = make_float4(0.f, 0.f, 0.f, 0.f);
    int k = beg + (lane >> 3);
    for (; k + 8 < end; k += 16) {
        int key0 = srcs2[k], key1 = srcs2[k + 8];
        int s0 = key0 >> 3, s1 = key1 >> 3;
        int g0 = key0 & 7, g1 = key1 & 7;
        float e0 = sh_inv[wid][g0], e1 = sh_inv[wid][g1];
        float4 v0 = *(const float4*)(y + ((size_t)(g0 >> 1) * NN + s0) * 64 + (g0 & 1) * 32 + q * 4);
        float4 v1 = *(const float4*)(y + ((size_t)(g1 >> 1) * NN + s1) * 64 + (g1 & 1) * 32 + q * 4);
        fmacc(acc, v0, e0);
        fmacc(acc, v1, e1);
    }
    if (k < end) {
        int key0 = srcs2[k];
        int s0 = key0 >> 3;
        int g0 = key0 & 7;
        float4 v0 = *(const float4*)(y + ((size_t)(g0 >> 1) * NN + s0) * 64 + (g0 & 1) * 32 + q * 4);
        fmacc(acc, v0, sh_inv[wid][g0]);
    }
    red4(acc, 8);
    red4(acc, 16);
    red4(acc, 32);
    if (lane < 8) {
        float4 prev = *(const float4*)(x3 + (size_t)n * 64 + q * 4);
        float4 b = *(const float4*)(bias + q * 4);
        float4 v;
        v.x = fmaxf(prev.x + acc.x + b.x, 0.f);
        v.y = fmaxf(prev.y + acc.y + b.y, 0.f);
        v.z = fmaxf(prev.z + acc.z + b.z, 0.f);
        v.w = fmaxf(prev.w + acc.w + b.w, 0.f);
        *(float4*)(x3 + (size_t)n * 64 + q * 4) = v;
    }
}

// ===== fused GAT aggregation in input space; alds[n][8] = (als[0..3], ald[0..3]) =====
template <int F, int LDX = F>
__global__ __launch_bounds__(256) void k_gatx(const int* __restrict__ rp,
                                              const int* __restrict__ srcs2,
                                              const float* __restrict__ alds,
                                              const float* __restrict__ X,
                                              float* __restrict__ msg) {
    constexpr int G = F / 4;    // lanes per edge-group (16 or 8)
    constexpr int NG = 64 / G;  // groups per wave (4 or 8)
    int wid = threadIdx.x >> 6, lane = threadIdx.x & 63;
    int n = blockIdx.x * 4 + wid;
    if (n >= NN) return;
    int g = lane / G, q = lane % G;
    float4 ald4 = *(const float4*)(alds + n * 8 + 4);
    float4 acc0 = make_float4(0.f, 0.f, 0.f, 0.f);
    float4 acc1 = acc0, acc2 = acc0, acc3 = acc0;
    float4 z = make_float4(0.f, 0.f, 0.f, 0.f);
    if (g == 0) {  // self loop
        float4 a4 = *(const float4*)(alds + n * 8);
        float4 xv = *(const float4*)(X + (size_t)n * LDX + q * 4);
        float p0 = __expf(leaky(a4.x + ald4.x));
        float p1 = __expf(leaky(a4.y + ald4.y));
        float p2 = __expf(leaky(a4.z + ald4.z));
        float p3 = __expf(leaky(a4.w + ald4.w));
        z = make_float4(p0, p1, p2, p3);
        fmacc(acc0, xv, p0);
        fmacc(acc1, xv, p1);
        fmacc(acc2, xv, p2);
        fmacc(acc3, xv, p3);
    }
    int beg = rp[n * RR], end = rp[n * RR + RR];
    int k = beg + g;
    for (; k + NG < end; k += 2 * NG) {
        int s0 = srcs2[k] >> 3, s1 = srcs2[k + NG] >> 3;
        float4 a0 = *(const float4*)(alds + s0 * 8);
        float4 a1 = *(const float4*)(alds + s1 * 8);
        float4 x0 = *(const float4*)(X + (size_t)s0 * LDX + q * 4);
        float4 x1v = *(const float4*)(X + (size_t)s1 * LDX + q * 4);
        float p00 = __expf(leaky(a0.x + ald4.x)), p01 = __expf(leaky(a0.y + ald4.y));
        float p02 = __expf(leaky(a0.z + ald4.z)), p03 = __expf(leaky(a0.w + ald4.w));
        float p10 = __expf(leaky(a1.x + ald4.x)), p11 = __expf(leaky(a1.y + ald4.y));
        float p12 = __expf(leaky(a1.z + ald4.z)), p13 = __expf(leaky(a1.w + ald4.w));
        z.x += p00 + p10;
        z.y += p01 + p11;
        z.z += p02 + p12;
        z.w += p03 + p13;
        fmacc(acc0, x0, p00);
        fmacc(acc1, x0, p01);
        fmacc(acc2, x0, p02);
        fmacc(acc3, x0, p03);
        fmacc(acc0, x1v, p10);
        fmacc(acc1, x1v, p11);
        fmacc(acc2, x1v, p12);
        fmacc(acc3, x1v, p13);
    }
    if (k < end) {
        int s0 = srcs2[k] >> 3;
        float4 a0 = *(const float4*)(alds + s0 * 8);
        float4 x0 = *(const float4*)(X + (size_t)s0 * LDX + q * 4);
        float p00 = __expf(leaky(a0.x + ald4.x)), p01 = __expf(leaky(a0.y + ald4.y));
        float p02 = __expf(leaky(a0.z + ald4.z)), p03 = __expf(leaky(a0.w + ald4.w));
        z.x += p00;
        z.y += p01;
        z.z += p02;
        z.w += p03;
        fmacc(acc0, x0, p00);
        fmacc(acc1, x0, p01);
        fmacc(acc2, x0, p02);
        fmacc(acc3, x0, p03);
    }
#pragma unroll
    for (int m = G; m < 64; m <<= 1) {
        red4(acc0, m);
        red4(acc1, m);
        red4(acc2, m);
        red4(acc3, m);
        red4(z, m);
    }
    if (g == 0) {
        float4 iz = make_float4(1.f / z.x, 1.f / z.y, 1.f / z.z, 1.f / z.w);
        float* mp = msg + (size_t)n * 4 * F + q * 4;
        *(float4*)(mp + 0 * F) = make_float4(acc0.x * iz.x, acc0.y * iz.x, acc0.z * iz.x, acc0.w * iz.x);
        *(float4*)(mp + 1 * F) = make_float4(acc1.x * iz.y, acc1.y * iz.y, acc1.z * iz.y, acc1.w * iz.y);
        *(float4*)(mp + 2 * F) = make_float4(acc2.x * iz.z, acc2.y * iz.z, acc2.z * iz.z, acc2.w * iz.z);
        *(float4*)(mp + 3 * F) = make_float4(acc3.x * iz.w, acc3.y * iz.w, acc3.z * iz.w, acc3.w * iz.w);
    }
}

extern "C" void kernel_launch(void* const* d_in, const int* in_sizes, int n_in,
                              void* d_out, int out_size, void* d_ws, size_t ws_size,
                              hipStream_t stream) {
    const float* x      = (const float*)d_in[0];
    const int*   ei     = (const int*)d_in[1];
    const int*   et     = (const int*)d_in[2];
    const float* basis1 = (const float*)d_in[3];
    const float* comp1  = (const float*)d_in[4];
    const float* root1  = (const float*)d_in[5];
    const float* brg1   = (const float*)d_in[6];
    const float* wg1    = (const float*)d_in[7];
    const float* asrc1  = (const float*)d_in[8];
    const float* adst1  = (const float*)d_in[9];
    const float* bg1    = (const float*)d_in[10];
    const float* basis2 = (const float*)d_in[11];
    const float* comp2  = (const float*)d_in[12];
    const float* root2  = (const float*)d_in[13];
    const float* brg2   = (const float*)d_in[14];
    const float* wg2    = (const float*)d_in[15];
    const float* asrc2  = (const float*)d_in[16];
    const float* adst2  = (const float*)d_in[17];
    const float* bg2    = (const float*)d_in[18];
    const int* src = ei;
    const int* dst = ei + EE;
    float* out = (float*)d_out;

    // ---- int region ----
    int* wsi = (int*)d_ws;
    size_t ioff = 0;
    auto ialloc = [&](size_t n) { int* p = wsi + ioff; ioff += (n + 3) & ~(size_t)3; return p; };
    int* cnt2 = ialloc(SEGS);  // reused as fill cursors (wo)
    int* rp   = ialloc(SEGS + 1);
    int* bsum = ialloc(2048);
    int* srcs2 = ialloc(EE);
    int* wo = cnt2;
    // ---- float region ----
    float* wsf = (float*)(wsi + ioff);
    size_t total_f = (ws_size - ioff * sizeof(int)) / sizeof(float);
    // P region: [x1/x3 : NN*64][ybuf : NN*256] contiguous so fused gemm writes mb*NN*64
    size_t P_f = (size_t)NN * 64 + (size_t)4 * NN * 64;
    size_t need_f = P_f + (size_t)NN * 128
                  + 36864 + 40960 + 16384 + 8192 + 4096 + 2048
                  + (size_t)NN * 8 + 64;
    if (total_f < need_f) return;  // loud fail: output stays zero
    size_t foff = 0;
    auto falloc = [&](size_t n) { float* p = wsf + foff; foff += (n + 3) & ~(size_t)3; return p; };
    float* P      = falloc(P_f);             // x1/x3 | ybuf
    float* x2     = falloc((size_t)NN * 128);
    float* Wcat1e = falloc(36864);           // [64][576]: root1 | W_r r=0..7
    float* Wcat2e = falloc(40960);           // [128][320]: root2(pad) | W_r pairs
    float* wg1r   = falloc(16384);
    float* Wstk   = falloc(8192);
    float* U1p    = falloc(4096);
    float* U2p    = falloc(2048);
    float* alds   = falloc((size_t)NN * 8);
    float* x1   = P;
    float* ybuf = P + (size_t)NN * 64;
    float* msg1 = ybuf;  // [n][4][64]
    float* msg2 = ybuf;  // [n][4][32]
    float* x3 = x1;      // stride 64, cols 32-63 zero-pad

    const int EB = (EE + 255) / 256;
    const int NB4 = (NN + 3) / 4;    // NN % 4 == 0 -> exact
    const int NT = (NN + 63) / 64;   // 782 (small gemm tiles)
    const int NT2 = (NN + 127) / 128;       // 391 (big gemm tiles)
    const int NT28 = ((NT2 + 7) / 8) * 8;   // 392: XCD-swizzle rounding

    // ---- CSR build ----
    hipMemsetAsync(cnt2, 0, SEGS * sizeof(int), stream);
    k_count2<<<EB, 256, 0, stream>>>(dst, et, cnt2);
    k_scanA<<<NBLK, 256, 0, stream>>>(cnt2, rp, bsum);
    k_scanB<<<1, 256, 0, stream>>>(bsum);
    k_scanC<<<NBLK, 256, 0, stream>>>(rp, bsum, wo);
    k_fill<<<EB, 256, 0, stream>>>(src, dst, et, wo, srcs2);
    k_weights<<<(2 * RR * 4096) / 256, 256, 0, stream>>>(basis1, comp1, basis2, comp2, Wcat1e, Wcat2e);
    k_prep<<<(43008 + 255) / 256, 256, 0, stream>>>(
        wg1, wg2, root1, root2, asrc1, adst1, asrc2, adst2, Wcat1e, Wcat2e, wg1r, Wstk, U1p, U2p);

    // ---- layer 1: RGCN(64->64)+relu; XCD-swizzled fused transform (root + rel 0-3), then 4-7 ----
    k_gemm128<64><<<NT28 * 5, 256, 0, stream>>>(x, 64, 0, Wcat1e, 576, 64,
                                                P, 64, (size_t)NN * 64, nullptr, 0, NT2, 5);
    k_agg1<<<NB4, 256, 0, stream>>>(rp, srcs2, ybuf, brg1, x1, 0, 4, 0);
    k_gemm128<64><<<NT28 * 4, 256, 0, stream>>>(x, 64, 0, Wcat1e + 320, 576, 64,
                                                ybuf, 64, (size_t)NN * 64, nullptr, 0, NT2, 4);
    k_agg1<<<NB4, 256, 0, stream>>>(rp, srcs2, ybuf, brg1, x1, 4, 4, 1);

    // ---- layer 2: GAT(64 -> 4x32 concat), aggregated in input space ----
    k_gemm64<64, 8><<<dim3(NT, 1), 256, 0, stream>>>(x1, 64, 0, U1p, 64, 0, alds, 8, 0,
                                                     nullptr, 0, NT, 0);
    k_gatx<64><<<NB4, 256, 0, stream>>>(rp, srcs2, alds, x1, msg1);
    k_gemm128<64, 32><<<dim3(NT2, 4), 256, 0, stream>>>(msg1, 256, 64, wg1r, 64, 4096,
                                                        x2, 128, 32, bg1, 32, NT2, 0);

    // ---- layer 3: RGCN(128->32)+relu; XCD-swizzled fused transform (root + 8 rel) ----
    k_gemm128<128><<<NT28 * 5, 256, 0, stream>>>(x2, 128, 0, Wcat2e, 320, 64,
                                                 P, 64, (size_t)NN * 64, nullptr, 0, NT2, 5);
    k_agg2<<<NB4, 256, 0, stream>>>(rp, srcs2, ybuf, brg2, x3);

    // ---- layer 4: GAT(32 -> 4x16, mean heads) + relu + tanh (fused into stack gemm) ----
    k_gemm64<32, 8><<<dim3(NT, 1), 256, 0, stream>>>(x3, 64, 0, U2p, 64, 0, alds, 8, 0,
                                                     nullptr, 0, NT, 0);
    k_gatx<32, 64><<<NB4, 256, 0, stream>>>(rp, srcs2, alds, x3, msg2);
    k_gemm64<128, 16, 1><<<dim3(NT, 1), 256, 0, stream>>>(msg2, 128, 0, Wstk, 64, 0,
                                                          out, 16, 0, bg2, 0, NT, 0);
}

// Round 15
// 535.433 us; speedup vs baseline: 1.0707x; 1.0688x over previous
//
#include <hip/hip_runtime.h>
#include <math.h>

#define NN 50000
#define EE 800000
#define RR 8
#define SLOPE 0.2f
#define SEGS (NN * RR)            /* 400000 per-(node,relation) segments */
#define NBLK ((SEGS + 255) / 256) /* 1563 scan blocks */

__device__ __forceinline__ float leaky(float v) { return v >= 0.f ? v : SLOPE * v; }

__device__ __forceinline__ void fmacc(float4& a, const float4& v, float p) {
    a.x = fmaf(v.x, p, a.x);
    a.y = fmaf(v.y, p, a.y);
    a.z = fmaf(v.z, p, a.z);
    a.w = fmaf(v.w, p, a.w);
}

__device__ __forceinline__ void red4(float4& a, int m) {
    a.x += __shfl_xor(a.x, m);
    a.y += __shfl_xor(a.y, m);
    a.z += __shfl_xor(a.z, m);
    a.w += __shfl_xor(a.w, m);
}

// ============================ CSR build ============================
__global__ void k_count2(const int* __restrict__ dst, const int* __restrict__ et,
                         int* __restrict__ cnt2) {
    int e = blockIdx.x * 256 + threadIdx.x;
    if (e < EE) atomicAdd(&cnt2[dst[e] * RR + et[e]], 1);
}

__global__ void k_scanA(const int* __restrict__ cnt2, int* __restrict__ rp,
                        int* __restrict__ bsum) {
    __shared__ int sh[256];
    int t = threadIdx.x;
    int i = blockIdx.x * 256 + t;
    int v = (i < SEGS) ? cnt2[i] : 0;
    sh[t] = v;
    __syncthreads();
    for (int off = 1; off < 256; off <<= 1) {
        int u = (t >= off) ? sh[t - off] : 0;
        __syncthreads();
        sh[t] += u;
        __syncthreads();
    }
    if (i < SEGS) rp[i] = sh[t] - v;
    if (t == 255) bsum[blockIdx.x] = sh[255];
}

__global__ void k_scanB(int* __restrict__ bsum) {
    __shared__ int sh[256];
    int t = threadIdx.x;
    int loc[8];
    int s = 0;
#pragma unroll
    for (int i = 0; i < 8; i++) {
        int idx = t * 8 + i;
        int v = (idx < NBLK) ? bsum[idx] : 0;
        loc[i] = v;
        s += v;
    }
    sh[t] = s;
    __syncthreads();
    for (int off = 1; off < 256; off <<= 1) {
        int u = (t >= off) ? sh[t - off] : 0;
        __syncthreads();
        sh[t] += u;
        __syncthreads();
    }
    int run = sh[t] - s;
#pragma unroll
    for (int i = 0; i < 8; i++) {
        int idx = t * 8 + i;
        if (idx < NBLK) {
            int v = loc[i];
            bsum[idx] = run;
            run += v;
        }
    }
}

__global__ void k_scanC(int* __restrict__ rp, const int* __restrict__ bsum,
                        int* __restrict__ wo) {
    int i = blockIdx.x * 256 + threadIdx.x;
    if (i < SEGS) {
        int v = rp[i] + bsum[blockIdx.x];
        rp[i] = v;
        wo[i] = v;
    }
    if (i == 0) rp[SEGS] = EE;
}

// fill packed keys: srcs2[pos] = src*8 + relation (single scattered store per edge)
__global__ void k_fill(const int* __restrict__ src, const int* __restrict__ dst,
                       const int* __restrict__ et, int* __restrict__ wo,
                       int* __restrict__ srcs2) {
    int e = blockIdx.x * 256 + threadIdx.x;
    if (e >= EE) return;
    int r = et[e];
    int seg = dst[e] * RR + r;
    int pos = atomicAdd(&wo[seg], 1);
    srcs2[pos] = (src[e] << 3) | r;
}

// ==== compose extended weights for layer 3 only: Wcat2e[128][320] ====
__global__ void k_weights(const float* __restrict__ basis2, const float* __restrict__ comp2,
                          float* __restrict__ Wcat2e) {
    int idx = blockIdx.x * 256 + threadIdx.x;
    if (idx < RR * 128 * 32) {
        int i = idx >> 8, rc = idx & 255;
        int r = rc >> 5, o = rc & 31;
        float acc = 0.f;
#pragma unroll
        for (int b = 0; b < 4; b++) acc += comp2[r * 4 + b] * basis2[b * 4096 + i * 32 + o];
        Wcat2e[i * 320 + 64 + rc] = acc;
    }
}

// ==== prep: padded weights, logit projections, stacked L1 basis+root Wb1[320][64] ====
__global__ void k_prep(const float* __restrict__ wg1, const float* __restrict__ wg2,
                       const float* __restrict__ root1, const float* __restrict__ root2,
                       const float* __restrict__ basis1,
                       const float* __restrict__ asrc1, const float* __restrict__ adst1,
                       const float* __restrict__ asrc2, const float* __restrict__ adst2,
                       float* __restrict__ Wcat2e, float* __restrict__ wg1r,
                       float* __restrict__ Wstk, float* __restrict__ Wr2p,
                       float* __restrict__ U1p, float* __restrict__ U2p,
                       float* __restrict__ Wb1) {
    int idx = blockIdx.x * 256 + threadIdx.x;
    if (idx < 16384) {  // wg1r[h][k][c] (c<32 valid)
        int h = idx >> 12, kc = idx & 4095;
        int k = kc >> 6, c = kc & 63;
        wg1r[idx] = (c < 32) ? wg1[k * 128 + h * 32 + c] : 0.f;
    } else if (idx < 24576) {  // Wstk[h*32+k][c] = wg2[k][h*16+c] (c<16 valid)
        int j = idx - 16384;
        int row = j >> 6, c = j & 63;
        int h = row >> 5, k = row & 31;
        Wstk[j] = (c < 16) ? wg2[k * 64 + h * 16 + c] : 0.f;
    } else if (idx < 32768) {  // Wr2p[k][c] (c<32 valid)
        int j = idx - 24576;
        int k = j >> 6, c = j & 63;
        Wr2p[j] = (c < 32) ? root2[k * 32 + c] : 0.f;
    } else if (idx < 40960) {  // Wcat2e root block: [128][col 0-63] = root2 zero-padded
        int j = idx - 32768;
        int k = j >> 6, c = j & 63;
        Wcat2e[k * 320 + c] = (c < 32) ? root2[k * 32 + c] : 0.f;
    } else if (idx < 45056) {  // U1p[k][j]: j<4 src head j, 4<=j<8 dst head j-4, else 0
        int j0 = idx - 40960;
        int k = j0 >> 6, j = j0 & 63;
        float s = 0.f;
        if (j < 8) {
            int h = j & 3;
            const float* a = (j < 4) ? asrc1 : adst1;
            for (int c = 0; c < 32; c++) s += wg1[k * 128 + h * 32 + c] * a[h * 32 + c];
        }
        U1p[j0] = s;
    } else if (idx < 47104) {  // U2p[k][j]
        int j0 = idx - 45056;
        int k = j0 >> 6, j = j0 & 63;
        float s = 0.f;
        if (j < 8) {
            int h = j & 3;
            const float* a = (j < 4) ? asrc2 : adst2;
            for (int c = 0; c < 16; c++) s += wg2[k * 64 + h * 16 + c] * a[h * 16 + c];
        }
        U2p[j0] = s;
    } else if (idx < 63488) {  // Wb1 rows 0-255 = basis1 [4][64][64] flat copy
        Wb1[idx - 47104] = basis1[idx - 47104];
    } else if (idx < 67584) {  // Wb1 rows 256-319 = root1
        Wb1[idx - 47104] = root1[idx - 63488];
    }
}

// ===== L1 basis-space gather: U[n][b][64] = sum_edges comp[r,b]*inv_cnt*x[src]; U[n][4][64]=x[n] =====
// 4 edge-groups x 16 lanes (float4 rows); per-wave LDS table w[r] = inv_cnt[r]*comp[r][0..3].
__global__ __launch_bounds__(256) void k_gagg1(const int* __restrict__ rp,
                                               const int* __restrict__ srcs2,
                                               const float* __restrict__ comp,
                                               const float* __restrict__ X,
                                               float* __restrict__ U) {
    __shared__ float4 sh_w[4][8];
    int wid = threadIdx.x >> 6, lane = threadIdx.x & 63;
    int n = blockIdx.x * 4 + wid;
    int rpv = (lane <= 8) ? rp[n * RR + lane] : 0;
    int nxt = __shfl(rpv, (lane + 1) & 63);
    if (lane < 8) {
        float inv = 1.f / (float)((nxt - rpv) > 0 ? (nxt - rpv) : 1);
        float4 c = *(const float4*)(comp + lane * 4);
        sh_w[wid][lane] = make_float4(c.x * inv, c.y * inv, c.z * inv, c.w * inv);
    }
    int q = lane & 15;
    int beg = rp[n * RR], end = rp[n * RR + RR];
    float4 a0 = make_float4(0.f, 0.f, 0.f, 0.f);
    float4 a1 = a0, a2 = a0, a3 = a0;
    int k = beg + (lane >> 4);
    for (; k + 4 < end; k += 8) {
        int key0 = srcs2[k], key1 = srcs2[k + 4];
        float4 w0 = sh_w[wid][key0 & 7], w1 = sh_w[wid][key1 & 7];
        float4 v0 = *(const float4*)(X + (size_t)(key0 >> 3) * 64 + q * 4);
        float4 v1 = *(const float4*)(X + (size_t)(key1 >> 3) * 64 + q * 4);
        fmacc(a0, v0, w0.x);
        fmacc(a1, v0, w0.y);
        fmacc(a2, v0, w0.z);
        fmacc(a3, v0, w0.w);
        fmacc(a0, v1, w1.x);
        fmacc(a1, v1, w1.y);
        fmacc(a2, v1, w1.z);
        fmacc(a3, v1, w1.w);
    }
    if (k < end) {
        int key0 = srcs2[k];
        float4 w0 = sh_w[wid][key0 & 7];
        float4 v0 = *(const float4*)(X + (size_t)(key0 >> 3) * 64 + q * 4);
        fmacc(a0, v0, w0.x);
        fmacc(a1, v0, w0.y);
        fmacc(a2, v0, w0.z);
        fmacc(a3, v0, w0.w);
    }
    red4(a0, 16); red4(a0, 32);
    red4(a1, 16); red4(a1, 32);
    red4(a2, 16); red4(a2, 32);
    red4(a3, 16); red4(a3, 32);
    if (lane < 16) {
        float* un = U + (size_t)n * 320;
        *(float4*)(un + 0 * 64 + q * 4) = a0;
        *(float4*)(un + 1 * 64 + q * 4) = a1;
        *(float4*)(un + 2 * 64 + q * 4) = a2;
        *(float4*)(un + 3 * 64 + q * 4) = a3;
        *(float4*)(un + 256 + q * 4) = *(const float4*)(X + (size_t)n * 64 + q * 4);
    }
}

// ============ big tiled GEMM: 128 nodes x 64 cols per block, 8x4 per thread ============
// Xs transposed+swizzled; mbcnt>0 -> XCD-grouped 1-D grid. ACT: 0=none, 2=relu(x+bias).
template <int KTOT, int MV = 64, int ACT = 0>
__global__ __launch_bounds__(256) void k_gemm128(const float* __restrict__ X, int ldX, int xmb,
                                                 const float* __restrict__ B, int ldB, int bmb,
                                                 float* __restrict__ Y, int ldY, size_t ymb,
                                                 const float* __restrict__ bias, int biasmb,
                                                 int nt, int mbcnt) {
    constexpr int Kc = (KTOT < 64) ? KTOT : 64;
    constexpr int KQ = Kc / 4;
    __shared__ __align__(16) float Xs[Kc * 136];
    __shared__ __align__(16) float Ws[Kc * 68];
    const int tid = threadIdx.x;
    const int tn8 = (tid >> 4) * 8;
    const int tm4 = (tid & 15) * 4;
    int tile, mb;
    if (mbcnt) {
        int b = blockIdx.x;
        int xcd = b & 7, slot = b >> 3;
        tile = (slot / mbcnt) * 8 + xcd;
        mb = slot % mbcnt;
        if (tile >= nt) return;  // block-uniform early exit (before any barrier)
    } else {
        tile = blockIdx.x;
        mb = blockIdx.y;
    }
    const int n0 = tile * 128;
    const float* Bm = B + (size_t)mb * bmb;
    const float* Xm = X + (size_t)mb * xmb;

    float acc[8][4];
#pragma unroll
    for (int a = 0; a < 8; a++)
#pragma unroll
        for (int b = 0; b < 4; b++) acc[a][b] = 0.f;

    for (int kk = 0; kk < KTOT; kk += Kc) {
        if (kk) __syncthreads();
        for (int i = tid; i < 128 * KQ; i += 256) {
            int nl = i / KQ, kq = i % KQ;
            float4 v = make_float4(0.f, 0.f, 0.f, 0.f);
            if (n0 + nl < NN)
                v = *reinterpret_cast<const float4*>(Xm + (size_t)(n0 + nl) * ldX + kk + 4 * kq);
            int col = (nl + 4 * kq) & 127;
            Xs[(4 * kq + 0) * 136 + col] = v.x;
            Xs[(4 * kq + 1) * 136 + col] = v.y;
            Xs[(4 * kq + 2) * 136 + col] = v.z;
            Xs[(4 * kq + 3) * 136 + col] = v.w;
        }
        for (int i = tid; i < Kc * 16; i += 256) {
            int kl = i >> 4, cq = i & 15;
            float4 v = *reinterpret_cast<const float4*>(Bm + (size_t)(kk + kl) * ldB + 4 * cq);
            *reinterpret_cast<float4*>(&Ws[kl * 68 + 4 * cq]) = v;
        }
        __syncthreads();
#pragma unroll 4
        for (int k = 0; k < Kc; k++) {
            float4 xq0 = *reinterpret_cast<const float4*>(&Xs[k * 136 + ((tn8 + (k & ~3)) & 127)]);
            float4 xq1 = *reinterpret_cast<const float4*>(&Xs[k * 136 + ((tn8 + 4 + (k & ~3)) & 127)]);
            float4 wq = *reinterpret_cast<const float4*>(&Ws[k * 68 + tm4]);
            float xa[8] = {xq0.x, xq0.y, xq0.z, xq0.w, xq1.x, xq1.y, xq1.z, xq1.w};
            float wa[4] = {wq.x, wq.y, wq.z, wq.w};
#pragma unroll
            for (int a = 0; a < 8; a++)
#pragma unroll
                for (int b = 0; b < 4; b++) acc[a][b] += xa[a] * wa[b];
        }
    }
    if (MV == 64 || tm4 < MV) {
        float4 bv = make_float4(0.f, 0.f, 0.f, 0.f);
        if (bias) bv = *reinterpret_cast<const float4*>(bias + (size_t)mb * biasmb + tm4);
#pragma unroll
        for (int a = 0; a < 8; a++) {
            int n = n0 + tn8 + a;
            if (n < NN) {
                float4 v = make_float4(acc[a][0] + bv.x, acc[a][1] + bv.y,
                                       acc[a][2] + bv.z, acc[a][3] + bv.w);
                if (ACT == 2) {
                    v.x = fmaxf(v.x, 0.f);
                    v.y = fmaxf(v.y, 0.f);
                    v.z = fmaxf(v.z, 0.f);
                    v.w = fmaxf(v.w, 0.f);
                }
                *reinterpret_cast<float4*>(Y + (size_t)mb * ymb + (size_t)n * ldY + tm4) = v;
            }
        }
    }
}

// ============ small tiled GEMM (64x64 tile, 4x4/thread) — proven R12 kernel ============
template <int KTOT, int MV = 64, int ACT = 0>
__global__ __launch_bounds__(256) void k_gemm64(const float* __restrict__ X, int ldX, int xmb,
                                                const float* __restrict__ B, int ldB, int bmb,
                                                float* __restrict__ Y, int ldY, size_t ymb,
                                                const float* __restrict__ bias, int biasmb,
                                                int nt, int mbcnt) {
    constexpr int Kc = (KTOT < 64) ? KTOT : 64;
    constexpr int KQ = Kc / 4;
    __shared__ __align__(16) float Xs[Kc * 68];
    __shared__ __align__(16) float Ws[Kc * 68];
    const int tid = threadIdx.x;
    const int tn4 = (tid >> 4) * 4;
    const int tm4 = (tid & 15) * 4;
    int tile, mb;
    if (mbcnt) {
        int b = blockIdx.x;
        int xcd = b & 7, slot = b >> 3;
        tile = (slot / mbcnt) * 8 + xcd;
        mb = slot % mbcnt;
        if (tile >= nt) return;
    } else {
        tile = blockIdx.x;
        mb = blockIdx.y;
    }
    const int n0 = tile * 64;
    const float* Bm = B + (size_t)mb * bmb;
    const float* Xm = X + (size_t)mb * xmb;

    float acc[4][4];
#pragma unroll
    for (int a = 0; a < 4; a++)
#pragma unroll
        for (int b = 0; b < 4; b++) acc[a][b] = 0.f;

    for (int kk = 0; kk < KTOT; kk += Kc) {
        if (kk) __syncthreads();
        for (int i = tid; i < 64 * KQ; i += 256) {
            int nl = i / KQ, kq = i % KQ;
            float4 v = make_float4(0.f, 0.f, 0.f, 0.f);
            if (n0 + nl < NN)
                v = *reinterpret_cast<const float4*>(Xm + (size_t)(n0 + nl) * ldX + kk + 4 * kq);
            int col = (nl + 4 * kq) & 63;
            Xs[(4 * kq + 0) * 68 + col] = v.x;
            Xs[(4 * kq + 1) * 68 + col] = v.y;
            Xs[(4 * kq + 2) * 68 + col] = v.z;
            Xs[(4 * kq + 3) * 68 + col] = v.w;
        }
        for (int i = tid; i < Kc * 16; i += 256) {
            int kl = i >> 4, cq = i & 15;
            float4 v = *reinterpret_cast<const float4*>(Bm + (size_t)(kk + kl) * ldB + 4 * cq);
            *reinterpret_cast<float4*>(&Ws[kl * 68 + 4 * cq]) = v;
        }
        __syncthreads();
#pragma unroll 4
        for (int k = 0; k < Kc; k++) {
            float4 xq = *reinterpret_cast<const float4*>(&Xs[k * 68 + ((tn4 + (k & ~3)) & 63)]);
            float4 wq = *reinterpret_cast<const float4*>(&Ws[k * 68 + tm4]);
            float xa[4] = {xq.x, xq.y, xq.z, xq.w};
            float wa[4] = {wq.x, wq.y, wq.z, wq.w};
#pragma unroll
            for (int a = 0; a < 4; a++)
#pragma unroll
                for (int b = 0; b < 4; b++) acc[a][b] += xa[a] * wa[b];
        }
    }
    if (MV == 64 || tm4 < MV) {
        float4 bv = make_float4(0.f, 0.f, 0.f, 0.f);
        if (bias) bv = *reinterpret_cast<const float4*>(bias + (size_t)mb * biasmb + tm4);
#pragma unroll
        for (int a = 0; a < 4; a++) {
            int n = n0 + tn4 + a;
            if (n < NN) {
                float4 v;
                if (ACT == 1) {
                    v.x = tanhf(fmaxf(0.25f * acc[a][0] + bv.x, 0.f));
                    v.y = tanhf(fmaxf(0.25f * acc[a][1] + bv.y, 0.f));
                    v.z = tanhf(fmaxf(0.25f * acc[a][2] + bv.z, 0.f));
                    v.w = tanhf(fmaxf(0.25f * acc[a][3] + bv.w, 0.f));
                } else {
                    v = make_float4(acc[a][0] + bv.x, acc[a][1] + bv.y,
                                    acc[a][2] + bv.z, acc[a][3] + bv.w);
                }
                *reinterpret_cast<float4*>(Y + (size_t)mb * ymb + (size_t)n * ldY + tm4) = v;
            }
        }
    }
}

// ===== aggregate 2: 8 edge-groups x 8 lanes; single pass; x3 stride 64 (cols 32-63 pad) =====
__global__ __launch_bounds__(256) void k_agg2(const int* __restrict__ rp,
                                              const int* __restrict__ srcs2,
                                              const float* __restrict__ y,
                                              const float* __restrict__ bias,
                                              float* __restrict__ x3) {
    __shared__ float sh_inv[4][8];
    int wid = threadIdx.x >> 6, lane = threadIdx.x & 63;
    int n = blockIdx.x * 4 + wid;
    int rpv = (lane <= 8) ? rp[n * RR + lane] : 0;
    int nxt = __shfl(rpv, (lane + 1) & 63);
    if (lane < 8) sh_inv[wid][lane] = 1.f / (float)((nxt - rpv) > 0 ? (nxt - rpv) : 1);
    int q = lane & 7;
    int beg = rp[n * RR], end = rp[n * RR + RR];
    float4 acc = make_float4(0.f, 0.f, 0.f, 0.f);
    int k = beg + (lane >> 3);
    for (; k + 8 < end; k += 16) {
        int key0 = srcs2[k], key1 = srcs2[k + 8];
        int s0 = key0 >> 3, s1 = key1 >> 3;
        int g0 = key0 & 7, g1 = key1 & 7;
        float e0 = sh_inv[wid][g0], e1 = sh_inv[wid][g1];
        float4 v0 = *(const float4*)(y + ((size_t)(g0 >> 1) * NN + s0) * 64 + (g0 & 1) * 32 + q * 4);
        float4 v1 = *(const float4*)(y + ((size_t)(g1 >> 1) * NN + s1) * 64 + (g1 & 1) * 32 + q * 4);
        fmacc(acc, v0, e0);
        fmacc(acc, v1, e1);
    }
    if (k < end) {
        int key0 = srcs2[k];
        int s0 = key0 >> 3;
        int g0 = key0 & 7;
        float4 v0 = *(const float4*)(y + ((size_t)(g0 >> 1) * NN + s0) * 64 + (g0 & 1) * 32 + q * 4);
        fmacc(acc, v0, sh_inv[wid][g0]);
    }
    red4(acc, 8);
    red4(acc, 16);
    red4(acc, 32);
    if (lane < 8) {
        float4 prev = *(const float4*)(x3 + (size_t)n * 64 + q * 4);
        float4 b = *(const float4*)(bias + q * 4);
        float4 v;
        v.x = fmaxf(prev.x + acc.x + b.x, 0.f);
        v.y = fmaxf(prev.y + acc.y + b.y, 0.f);
        v.z = fmaxf(prev.z + acc.z + b.z, 0.f);
        v.w = fmaxf(prev.w + acc.w + b.w, 0.f);
        *(float4*)(x3 + (size_t)n * 64 + q * 4) = v;
    }
}

// ===== fused GAT aggregation in input space; alds[n][8] = (als[0..3], ald[0..3]) =====
template <int F, int LDX = F>
__global__ __launch_bounds__(256) void k_gatx(const int* __restrict__ rp,
                                              const int* __restrict__ srcs2,
                                              const float* __restrict__ alds,
                                              const float* __restrict__ X,
                                              float* __restrict__ msg) {
    constexpr int G = F / 4;    // lanes per edge-group (16 or 8)
    constexpr int NG = 64 / G;  // groups per wave (4 or 8)
    int wid = threadIdx.x >> 6, lane = threadIdx.x & 63;
    int n = blockIdx.x * 4 + wid;
    if (n >= NN) return;
    int g = lane / G, q = lane % G;
    float4 ald4 = *(const float4*)(alds + n * 8 + 4);
    float4 acc0 = make_float4(0.f, 0.f, 0.f, 0.f);
    float4 acc1 = acc0, acc2 = acc0, acc3 = acc0;
    float4 z = make_float4(0.f, 0.f, 0.f, 0.f);
    if (g == 0) {  // self loop
        float4 a4 = *(const float4*)(alds + n * 8);
        float4 xv = *(const float4*)(X + (size_t)n * LDX + q * 4);
        float p0 = __expf(leaky(a4.x + ald4.x));
        float p1 = __expf(leaky(a4.y + ald4.y));
        float p2 = __expf(leaky(a4.z + ald4.z));
        float p3 = __expf(leaky(a4.w + ald4.w));
        z = make_float4(p0, p1, p2, p3);
        fmacc(acc0, xv, p0);
        fmacc(acc1, xv, p1);
        fmacc(acc2, xv, p2);
        fmacc(acc3, xv, p3);
    }
    int beg = rp[n * RR], end = rp[n * RR + RR];
    int k = beg + g;
    for (; k + NG < end; k += 2 * NG) {
        int s0 = srcs2[k] >> 3, s1 = srcs2[k + NG] >> 3;
        float4 a0 = *(const float4*)(alds + s0 * 8);
        float4 a1 = *(const float4*)(alds + s1 * 8);
        float4 x0 = *(const float4*)(X + (size_t)s0 * LDX + q * 4);
        float4 x1v = *(const float4*)(X + (size_t)s1 * LDX + q * 4);
        float p00 = __expf(leaky(a0.x + ald4.x)), p01 = __expf(leaky(a0.y + ald4.y));
        float p02 = __expf(leaky(a0.z + ald4.z)), p03 = __expf(leaky(a0.w + ald4.w));
        float p10 = __expf(leaky(a1.x + ald4.x)), p11 = __expf(leaky(a1.y + ald4.y));
        float p12 = __expf(leaky(a1.z + ald4.z)), p13 = __expf(leaky(a1.w + ald4.w));
        z.x += p00 + p10;
        z.y += p01 + p11;
        z.z += p02 + p12;
        z.w += p03 + p13;
        fmacc(acc0, x0, p00);
        fmacc(acc1, x0, p01);
        fmacc(acc2, x0, p02);
        fmacc(acc3, x0, p03);
        fmacc(acc0, x1v, p10);
        fmacc(acc1, x1v, p11);
        fmacc(acc2, x1v, p12);
        fmacc(acc3, x1v, p13);
    }
    if (k < end) {
        int s0 = srcs2[k] >> 3;
        float4 a0 = *(const float4*)(alds + s0 * 8);
        float4 x0 = *(const float4*)(X + (size_t)s0 * LDX + q * 4);
        float p00 = __expf(leaky(a0.x + ald4.x)), p01 = __expf(leaky(a0.y + ald4.y));
        float p02 = __expf(leaky(a0.z + ald4.z)), p03 = __expf(leaky(a0.w + ald4.w));
        z.x += p00;
        z.y += p01;
        z.z += p02;
        z.w += p03;
        fmacc(acc0, x0, p00);
        fmacc(acc1, x0, p01);
        fmacc(acc2, x0, p02);
        fmacc(acc3, x0, p03);
    }
#pragma unroll
    for (int m = G; m < 64; m <<= 1) {
        red4(acc0, m);
        red4(acc1, m);
        red4(acc2, m);
        red4(acc3, m);
        red4(z, m);
    }
    if (g == 0) {
        float4 iz = make_float4(1.f / z.x, 1.f / z.y, 1.f / z.z, 1.f / z.w);
        float* mp = msg + (size_t)n * 4 * F + q * 4;
        *(float4*)(mp + 0 * F) = make_float4(acc0.x * iz.x, acc0.y * iz.x, acc0.z * iz.x, acc0.w * iz.x);
        *(float4*)(mp + 1 * F) = make_float4(acc1.x * iz.y, acc1.y * iz.y, acc1.z * iz.y, acc1.w * iz.y);
        *(float4*)(mp + 2 * F) = make_float4(acc2.x * iz.z, acc2.y * iz.z, acc2.z * iz.z, acc2.w * iz.z);
        *(float4*)(mp + 3 * F) = make_float4(acc3.x * iz.w, acc3.y * iz.w, acc3.z * iz.w, acc3.w * iz.w);
    }
}

extern "C" void kernel_launch(void* const* d_in, const int* in_sizes, int n_in,
                              void* d_out, int out_size, void* d_ws, size_t ws_size,
                              hipStream_t stream) {
    const float* x      = (const float*)d_in[0];
    const int*   ei     = (const int*)d_in[1];
    const int*   et     = (const int*)d_in[2];
    const float* basis1 = (const float*)d_in[3];
    const float* comp1  = (const float*)d_in[4];
    const float* root1  = (const float*)d_in[5];
    const float* brg1   = (const float*)d_in[6];
    const float* wg1    = (const float*)d_in[7];
    const float* asrc1  = (const float*)d_in[8];
    const float* adst1  = (const float*)d_in[9];
    const float* bg1    = (const float*)d_in[10];
    const float* basis2 = (const float*)d_in[11];
    const float* comp2  = (const float*)d_in[12];
    const float* root2  = (const float*)d_in[13];
    const float* brg2   = (const float*)d_in[14];
    const float* wg2    = (const float*)d_in[15];
    const float* asrc2  = (const float*)d_in[16];
    const float* adst2  = (const float*)d_in[17];
    const float* bg2    = (const float*)d_in[18];
    const int* src = ei;
    const int* dst = ei + EE;
    float* out = (float*)d_out;

    // ---- int region ----
    int* wsi = (int*)d_ws;
    size_t ioff = 0;
    auto ialloc = [&](size_t n) { int* p = wsi + ioff; ioff += (n + 3) & ~(size_t)3; return p; };
    int* cnt2 = ialloc(SEGS);  // reused as fill cursors (wo)
    int* rp   = ialloc(SEGS + 1);
    int* bsum = ialloc(2048);
    int* srcs2 = ialloc(EE);
    int* wo = cnt2;
    // ---- float region ----
    float* wsf = (float*)(wsi + ioff);
    size_t total_f = (ws_size - ioff * sizeof(int)) / sizeof(float);
    // P region NN*320: L1 U[n][320]; then msg1 [0,NN*256); then [x3 | ybuf3]; then msg2
    size_t P_f = (size_t)NN * 320;
    size_t need_f = P_f + (size_t)NN * 128
                  + 40960 + 20480 + 16384 + 8192 + 8192 + 4096 + 2048
                  + (size_t)NN * 8 + 64;
    if (total_f < need_f) return;  // loud fail: output stays zero
    size_t foff = 0;
    auto falloc = [&](size_t n) { float* p = wsf + foff; foff += (n + 3) & ~(size_t)3; return p; };
    float* P      = falloc(P_f);
    float* x2     = falloc((size_t)NN * 128);
    float* Wcat2e = falloc(40960);           // [128][320]: root2(pad) | W_r pairs
    float* Wb1    = falloc(20480);           // [320][64]: basis1 rows | root1 rows
    float* wg1r   = falloc(16384);
    float* Wstk   = falloc(8192);
    float* Wr2p   = falloc(8192);
    float* U1p    = falloc(4096);
    float* U2p    = falloc(2048);
    float* alds   = falloc((size_t)NN * 8);
    float* Ubuf = P;                  // L1 basis-gather output [n][320]
    float* x1   = x2 + (size_t)NN * 64;  // dead before msg1-gemm overwrites x2 region
    float* msg1 = P;                  // [n][4][64] (U dead after u-gemm)
    float* x3   = P;                  // stride 64, cols 32-63 pad (L3)
    float* ybuf3 = P + (size_t)NN * 64;  // L3 transform out, 4*NN*64
    float* msg2 = P + (size_t)NN * 64;   // [n][4][32] (ybuf3 dead after agg2; disjoint from x3)

    const int EB = (EE + 255) / 256;
    const int NB4 = (NN + 3) / 4;    // NN % 4 == 0 -> exact
    const int NT = (NN + 63) / 64;   // 782 (small gemm tiles)
    const int NT2 = (NN + 127) / 128;       // 391 (big gemm tiles)
    const int NT28 = ((NT2 + 7) / 8) * 8;   // 392: XCD-swizzle rounding

    // ---- CSR build ----
    hipMemsetAsync(cnt2, 0, SEGS * sizeof(int), stream);
    k_count2<<<EB, 256, 0, stream>>>(dst, et, cnt2);
    k_scanA<<<NBLK, 256, 0, stream>>>(cnt2, rp, bsum);
    k_scanB<<<1, 256, 0, stream>>>(bsum);
    k_scanC<<<NBLK, 256, 0, stream>>>(rp, bsum, wo);
    k_fill<<<EB, 256, 0, stream>>>(src, dst, et, wo, srcs2);
    k_weights<<<(RR * 128 * 32) / 256, 256, 0, stream>>>(basis2, comp2, Wcat2e);
    k_prep<<<(67584 + 255) / 256, 256, 0, stream>>>(
        wg1, wg2, root1, root2, basis1, asrc1, adst1, asrc2, adst2,
        Wcat2e, wg1r, Wstk, Wr2p, U1p, U2p, Wb1);

    // ---- layer 1: RGCN(64->64)+relu via basis-space gather + one K=320 GEMM ----
    k_gagg1<<<NB4, 256, 0, stream>>>(rp, srcs2, comp1, x, Ubuf);
    k_gemm128<320, 64, 2><<<dim3(NT2, 1), 256, 0, stream>>>(Ubuf, 320, 0, Wb1, 64, 0,
                                                            x1, 64, 0, brg1, 0, NT2, 0);

    // ---- layer 2: GAT(64 -> 4x32 concat), aggregated in input space ----
    k_gemm64<64, 8><<<dim3(NT, 1), 256, 0, stream>>>(x1, 64, 0, U1p, 64, 0, alds, 8, 0,
                                                     nullptr, 0, NT, 0);
    k_gatx<64><<<NB4, 256, 0, stream>>>(rp, srcs2, alds, x1, msg1);
    k_gemm128<64, 32><<<dim3(NT2, 4), 256, 0, stream>>>(msg1, 256, 64, wg1r, 64, 4096,
                                                        x2, 128, 32, bg1, 32, NT2, 0);

    // ---- layer 3: RGCN(128->32)+relu; XCD-swizzled fused transform (root + 8 rel) ----
    k_gemm128<128><<<NT28 * 5, 256, 0, stream>>>(x2, 128, 0, Wcat2e, 320, 64,
                                                 P, 64, (size_t)NN * 64, nullptr, 0, NT2, 5);
    k_agg2<<<NB4, 256, 0, stream>>>(rp, srcs2, ybuf3, brg2, x3);

    // ---- layer 4: GAT(32 -> 4x16, mean heads) + relu + tanh (fused into stack gemm) ----
    k_gemm64<32, 8><<<dim3(NT, 1), 256, 0, stream>>>(x3, 64, 0, U2p, 64, 0, alds, 8, 0,
                                                     nullptr, 0, NT, 0);
    k_gatx<32, 64><<<NB4, 256, 0, stream>>>(rp, srcs2, alds, x3, msg2);
    k_gemm64<128, 16, 1><<<dim3(NT, 1), 256, 0, stream>>>(msg2, 128, 0, Wstk, 64, 0,
                                                          out, 16, 0, bg2, 0, NT, 0);
}

// Round 16
// 530.973 us; speedup vs baseline: 1.0797x; 1.0084x over previous
//
#include <hip/hip_runtime.h>
#include <math.h>

#define NN 50000
#define EE 800000
#define RR 8
#define SLOPE 0.2f
#define SEGS (NN * RR)            /* 400000 per-(node,relation) segments */
#define NBLK ((SEGS + 255) / 256) /* 1563 scan blocks */

__device__ __forceinline__ float leaky(float v) { return v >= 0.f ? v : SLOPE * v; }

__device__ __forceinline__ void fmacc(float4& a, const float4& v, float p) {
    a.x = fmaf(v.x, p, a.x);
    a.y = fmaf(v.y, p, a.y);
    a.z = fmaf(v.z, p, a.z);
    a.w = fmaf(v.w, p, a.w);
}

__device__ __forceinline__ void red4(float4& a, int m) {
    a.x += __shfl_xor(a.x, m);
    a.y += __shfl_xor(a.y, m);
    a.z += __shfl_xor(a.z, m);
    a.w += __shfl_xor(a.w, m);
}

// ============================ CSR build ============================
__global__ void k_count2(const int* __restrict__ dst, const int* __restrict__ et,
                         int* __restrict__ cnt2) {
    int e = blockIdx.x * 256 + threadIdx.x;
    if (e < EE) atomicAdd(&cnt2[dst[e] * RR + et[e]], 1);
}

__global__ void k_scanA(const int* __restrict__ cnt2, int* __restrict__ rp,
                        int* __restrict__ bsum) {
    __shared__ int sh[256];
    int t = threadIdx.x;
    int i = blockIdx.x * 256 + t;
    int v = (i < SEGS) ? cnt2[i] : 0;
    sh[t] = v;
    __syncthreads();
    for (int off = 1; off < 256; off <<= 1) {
        int u = (t >= off) ? sh[t - off] : 0;
        __syncthreads();
        sh[t] += u;
        __syncthreads();
    }
    if (i < SEGS) rp[i] = sh[t] - v;
    if (t == 255) bsum[blockIdx.x] = sh[255];
}

__global__ void k_scanB(int* __restrict__ bsum) {
    __shared__ int sh[256];
    int t = threadIdx.x;
    int loc[8];
    int s = 0;
#pragma unroll
    for (int i = 0; i < 8; i++) {
        int idx = t * 8 + i;
        int v = (idx < NBLK) ? bsum[idx] : 0;
        loc[i] = v;
        s += v;
    }
    sh[t] = s;
    __syncthreads();
    for (int off = 1; off < 256; off <<= 1) {
        int u = (t >= off) ? sh[t - off] : 0;
        __syncthreads();
        sh[t] += u;
        __syncthreads();
    }
    int run = sh[t] - s;
#pragma unroll
    for (int i = 0; i < 8; i++) {
        int idx = t * 8 + i;
        if (idx < NBLK) {
            int v = loc[i];
            bsum[idx] = run;
            run += v;
        }
    }
}

__global__ void k_scanC(int* __restrict__ rp, const int* __restrict__ bsum,
                        int* __restrict__ wo) {
    int i = blockIdx.x * 256 + threadIdx.x;
    if (i < SEGS) {
        int v = rp[i] + bsum[blockIdx.x];
        rp[i] = v;
        wo[i] = v;
    }
    if (i == 0) rp[SEGS] = EE;
}

// fill packed keys: srcs2[pos] = src*8 + relation (single scattered store per edge)
__global__ void k_fill(const int* __restrict__ src, const int* __restrict__ dst,
                       const int* __restrict__ et, int* __restrict__ wo,
                       int* __restrict__ srcs2) {
    int e = blockIdx.x * 256 + threadIdx.x;
    if (e >= EE) return;
    int r = et[e];
    int seg = dst[e] * RR + r;
    int pos = atomicAdd(&wo[seg], 1);
    srcs2[pos] = (src[e] << 3) | r;
}

// ==== prep (merged): padded weights, logit projections, stacked Wb1, Wcat2e compose ====
__global__ void k_prep(const float* __restrict__ wg1, const float* __restrict__ wg2,
                       const float* __restrict__ root1, const float* __restrict__ root2,
                       const float* __restrict__ basis1, const float* __restrict__ basis2,
                       const float* __restrict__ comp2,
                       const float* __restrict__ asrc1, const float* __restrict__ adst1,
                       const float* __restrict__ asrc2, const float* __restrict__ adst2,
                       float* __restrict__ Wcat2e, float* __restrict__ wg1r,
                       float* __restrict__ Wstk, float* __restrict__ U1p,
                       float* __restrict__ U2p, float* __restrict__ Wb1) {
    int idx = blockIdx.x * 256 + threadIdx.x;
    if (idx < 16384) {  // wg1r[h][k][c] (c<32 valid)
        int h = idx >> 12, kc = idx & 4095;
        int k = kc >> 6, c = kc & 63;
        wg1r[idx] = (c < 32) ? wg1[k * 128 + h * 32 + c] : 0.f;
    } else if (idx < 24576) {  // Wstk[h*32+k][c] = wg2[k][h*16+c] (c<16 valid)
        int j = idx - 16384;
        int row = j >> 6, c = j & 63;
        int h = row >> 5, k = row & 31;
        Wstk[j] = (c < 16) ? wg2[k * 64 + h * 16 + c] : 0.f;
    } else if (idx < 32768) {  // Wcat2e root block: [128][col 0-63] = root2 zero-padded
        int j = idx - 24576;
        int k = j >> 6, c = j & 63;
        Wcat2e[k * 320 + c] = (c < 32) ? root2[k * 32 + c] : 0.f;
    } else if (idx < 36864) {  // U1p[k][j]: j<4 src head j, 4<=j<8 dst head j-4, else 0
        int j0 = idx - 32768;
        int k = j0 >> 6, j = j0 & 63;
        float s = 0.f;
        if (j < 8) {
            int h = j & 3;
            const float* a = (j < 4) ? asrc1 : adst1;
            for (int c = 0; c < 32; c++) s += wg1[k * 128 + h * 32 + c] * a[h * 32 + c];
        }
        U1p[j0] = s;
    } else if (idx < 38912) {  // U2p[k][j]
        int j0 = idx - 36864;
        int k = j0 >> 6, j = j0 & 63;
        float s = 0.f;
        if (j < 8) {
            int h = j & 3;
            const float* a = (j < 4) ? asrc2 : adst2;
            for (int c = 0; c < 16; c++) s += wg2[k * 64 + h * 16 + c] * a[h * 16 + c];
        }
        U2p[j0] = s;
    } else if (idx < 55296) {  // Wb1 rows 0-255 = basis1 [4][64][64] flat copy
        Wb1[idx - 38912] = basis1[idx - 38912];
    } else if (idx < 59392) {  // Wb1 rows 256-319 = root1
        Wb1[idx - 38912] = root1[idx - 55296];
    } else if (idx < 92160) {  // Wcat2e basis-composed block: [128][col 64-319]
        int j = idx - 59392;
        int i = j >> 8, rc = j & 255;
        int r = rc >> 5, o = rc & 31;
        float acc = 0.f;
#pragma unroll
        for (int b = 0; b < 4; b++) acc += comp2[r * 4 + b] * basis2[b * 4096 + i * 32 + o];
        Wcat2e[i * 320 + 64 + rc] = acc;
    }
}

// ===== L1 basis-space gather: U[n][b][64] = sum_edges comp[r,b]*inv_cnt*x[src]; U[n][4][64]=x[n] =====
__global__ __launch_bounds__(256) void k_gagg1(const int* __restrict__ rp,
                                               const int* __restrict__ srcs2,
                                               const float* __restrict__ comp,
                                               const float* __restrict__ X,
                                               float* __restrict__ U) {
    __shared__ float4 sh_w[4][8];
    int wid = threadIdx.x >> 6, lane = threadIdx.x & 63;
    int n = blockIdx.x * 4 + wid;
    int rpv = (lane <= 8) ? rp[n * RR + lane] : 0;
    int nxt = __shfl(rpv, (lane + 1) & 63);
    if (lane < 8) {
        float inv = 1.f / (float)((nxt - rpv) > 0 ? (nxt - rpv) : 1);
        float4 c = *(const float4*)(comp + lane * 4);
        sh_w[wid][lane] = make_float4(c.x * inv, c.y * inv, c.z * inv, c.w * inv);
    }
    int q = lane & 15;
    int beg = rp[n * RR], end = rp[n * RR + RR];
    float4 a0 = make_float4(0.f, 0.f, 0.f, 0.f);
    float4 a1 = a0, a2 = a0, a3 = a0;
    int k = beg + (lane >> 4);
    for (; k + 4 < end; k += 8) {
        int key0 = srcs2[k], key1 = srcs2[k + 4];
        float4 w0 = sh_w[wid][key0 & 7], w1 = sh_w[wid][key1 & 7];
        float4 v0 = *(const float4*)(X + (size_t)(key0 >> 3) * 64 + q * 4);
        float4 v1 = *(const float4*)(X + (size_t)(key1 >> 3) * 64 + q * 4);
        fmacc(a0, v0, w0.x);
        fmacc(a1, v0, w0.y);
        fmacc(a2, v0, w0.z);
        fmacc(a3, v0, w0.w);
        fmacc(a0, v1, w1.x);
        fmacc(a1, v1, w1.y);
        fmacc(a2, v1, w1.z);
        fmacc(a3, v1, w1.w);
    }
    if (k < end) {
        int key0 = srcs2[k];
        float4 w0 = sh_w[wid][key0 & 7];
        float4 v0 = *(const float4*)(X + (size_t)(key0 >> 3) * 64 + q * 4);
        fmacc(a0, v0, w0.x);
        fmacc(a1, v0, w0.y);
        fmacc(a2, v0, w0.z);
        fmacc(a3, v0, w0.w);
    }
    red4(a0, 16); red4(a0, 32);
    red4(a1, 16); red4(a1, 32);
    red4(a2, 16); red4(a2, 32);
    red4(a3, 16); red4(a3, 32);
    if (lane < 16) {
        float* un = U + (size_t)n * 320;
        *(float4*)(un + 0 * 64 + q * 4) = a0;
        *(float4*)(un + 1 * 64 + q * 4) = a1;
        *(float4*)(un + 2 * 64 + q * 4) = a2;
        *(float4*)(un + 3 * 64 + q * 4) = a3;
        *(float4*)(un + 256 + q * 4) = *(const float4*)(X + (size_t)n * 64 + q * 4);
    }
}

// ============ big tiled GEMM: 128 nodes x 64 cols; Kc=32 (26 KB LDS -> 6 blocks/CU) ============
// Xs transposed+swizzled; mbcnt>0 -> XCD-grouped 1-D grid. ACT: 0=none, 2=relu(x+bias).
template <int KTOT, int MV = 64, int ACT = 0>
__global__ __launch_bounds__(256) void k_gemm128(const float* __restrict__ X, int ldX, int xmb,
                                                 const float* __restrict__ B, int ldB, int bmb,
                                                 float* __restrict__ Y, int ldY, size_t ymb,
                                                 const float* __restrict__ bias, int biasmb,
                                                 int nt, int mbcnt) {
    constexpr int Kc = (KTOT < 32) ? KTOT : 32;
    constexpr int KQ = Kc / 4;
    __shared__ __align__(16) float Xs[Kc * 136];
    __shared__ __align__(16) float Ws[Kc * 68];
    const int tid = threadIdx.x;
    const int tn8 = (tid >> 4) * 8;
    const int tm4 = (tid & 15) * 4;
    int tile, mb;
    if (mbcnt) {
        int b = blockIdx.x;
        int xcd = b & 7, slot = b >> 3;
        tile = (slot / mbcnt) * 8 + xcd;
        mb = slot % mbcnt;
        if (tile >= nt) return;  // block-uniform early exit (before any barrier)
    } else {
        tile = blockIdx.x;
        mb = blockIdx.y;
    }
    const int n0 = tile * 128;
    const float* Bm = B + (size_t)mb * bmb;
    const float* Xm = X + (size_t)mb * xmb;

    float acc[8][4];
#pragma unroll
    for (int a = 0; a < 8; a++)
#pragma unroll
        for (int b = 0; b < 4; b++) acc[a][b] = 0.f;

    for (int kk = 0; kk < KTOT; kk += Kc) {
        if (kk) __syncthreads();
        for (int i = tid; i < 128 * KQ; i += 256) {
            int nl = i / KQ, kq = i % KQ;
            float4 v = make_float4(0.f, 0.f, 0.f, 0.f);
            if (n0 + nl < NN)
                v = *reinterpret_cast<const float4*>(Xm + (size_t)(n0 + nl) * ldX + kk + 4 * kq);
            int col = (nl + 4 * kq) & 127;
            Xs[(4 * kq + 0) * 136 + col] = v.x;
            Xs[(4 * kq + 1) * 136 + col] = v.y;
            Xs[(4 * kq + 2) * 136 + col] = v.z;
            Xs[(4 * kq + 3) * 136 + col] = v.w;
        }
        for (int i = tid; i < Kc * 16; i += 256) {
            int kl = i >> 4, cq = i & 15;
            float4 v = *reinterpret_cast<const float4*>(Bm + (size_t)(kk + kl) * ldB + 4 * cq);
            *reinterpret_cast<float4*>(&Ws[kl * 68 + 4 * cq]) = v;
        }
        __syncthreads();
#pragma unroll 4
        for (int k = 0; k < Kc; k++) {
            float4 xq0 = *reinterpret_cast<const float4*>(&Xs[k * 136 + ((tn8 + (k & ~3)) & 127)]);
            float4 xq1 = *reinterpret_cast<const float4*>(&Xs[k * 136 + ((tn8 + 4 + (k & ~3)) & 127)]);
            float4 wq = *reinterpret_cast<const float4*>(&Ws[k * 68 + tm4]);
            float xa[8] = {xq0.x, xq0.y, xq0.z, xq0.w, xq1.x, xq1.y, xq1.z, xq1.w};
            float wa[4] = {wq.x, wq.y, wq.z, wq.w};
#pragma unroll
            for (int a = 0; a < 8; a++)
#pragma unroll
                for (int b = 0; b < 4; b++) acc[a][b] += xa[a] * wa[b];
        }
    }
    if (MV == 64 || tm4 < MV) {
        float4 bv = make_float4(0.f, 0.f, 0.f, 0.f);
        if (bias) bv = *reinterpret_cast<const float4*>(bias + (size_t)mb * biasmb + tm4);
#pragma unroll
        for (int a = 0; a < 8; a++) {
            int n = n0 + tn8 + a;
            if (n < NN) {
                float4 v = make_float4(acc[a][0] + bv.x, acc[a][1] + bv.y,
                                       acc[a][2] + bv.z, acc[a][3] + bv.w);
                if (ACT == 2) {
                    v.x = fmaxf(v.x, 0.f);
                    v.y = fmaxf(v.y, 0.f);
                    v.z = fmaxf(v.z, 0.f);
                    v.w = fmaxf(v.w, 0.f);
                }
                *reinterpret_cast<float4*>(Y + (size_t)mb * ymb + (size_t)n * ldY + tm4) = v;
            }
        }
    }
}

// ============ small tiled GEMM (64x64 tile, 4x4/thread) — proven R12 kernel ============
template <int KTOT, int MV = 64, int ACT = 0>
__global__ __launch_bounds__(256) void k_gemm64(const float* __restrict__ X, int ldX, int xmb,
                                                const float* __restrict__ B, int ldB, int bmb,
                                                float* __restrict__ Y, int ldY, size_t ymb,
                                                const float* __restrict__ bias, int biasmb,
                                                int nt, int mbcnt) {
    constexpr int Kc = (KTOT < 64) ? KTOT : 64;
    constexpr int KQ = Kc / 4;
    __shared__ __align__(16) float Xs[Kc * 68];
    __shared__ __align__(16) float Ws[Kc * 68];
    const int tid = threadIdx.x;
    const int tn4 = (tid >> 4) * 4;
    const int tm4 = (tid & 15) * 4;
    int tile, mb;
    if (mbcnt) {
        int b = blockIdx.x;
        int xcd = b & 7, slot = b >> 3;
        tile = (slot / mbcnt) * 8 + xcd;
        mb = slot % mbcnt;
        if (tile >= nt) return;
    } else {
        tile = blockIdx.x;
        mb = blockIdx.y;
    }
    const int n0 = tile * 64;
    const float* Bm = B + (size_t)mb * bmb;
    const float* Xm = X + (size_t)mb * xmb;

    float acc[4][4];
#pragma unroll
    for (int a = 0; a < 4; a++)
#pragma unroll
        for (int b = 0; b < 4; b++) acc[a][b] = 0.f;

    for (int kk = 0; kk < KTOT; kk += Kc) {
        if (kk) __syncthreads();
        for (int i = tid; i < 64 * KQ; i += 256) {
            int nl = i / KQ, kq = i % KQ;
            float4 v = make_float4(0.f, 0.f, 0.f, 0.f);
            if (n0 + nl < NN)
                v = *reinterpret_cast<const float4*>(Xm + (size_t)(n0 + nl) * ldX + kk + 4 * kq);
            int col = (nl + 4 * kq) & 63;
            Xs[(4 * kq + 0) * 68 + col] = v.x;
            Xs[(4 * kq + 1) * 68 + col] = v.y;
            Xs[(4 * kq + 2) * 68 + col] = v.z;
            Xs[(4 * kq + 3) * 68 + col] = v.w;
        }
        for (int i = tid; i < Kc * 16; i += 256) {
            int kl = i >> 4, cq = i & 15;
            float4 v = *reinterpret_cast<const float4*>(Bm + (size_t)(kk + kl) * ldB + 4 * cq);
            *reinterpret_cast<float4*>(&Ws[kl * 68 + 4 * cq]) = v;
        }
        __syncthreads();
#pragma unroll 4
        for (int k = 0; k < Kc; k++) {
            float4 xq = *reinterpret_cast<const float4*>(&Xs[k * 68 + ((tn4 + (k & ~3)) & 63)]);
            float4 wq = *reinterpret_cast<const float4*>(&Ws[k * 68 + tm4]);
            float xa[4] = {xq.x, xq.y, xq.z, xq.w};
            float wa[4] = {wq.x, wq.y, wq.z, wq.w};
#pragma unroll
            for (int a = 0; a < 4; a++)
#pragma unroll
                for (int b = 0; b < 4; b++) acc[a][b] += xa[a] * wa[b];
        }
    }
    if (MV == 64 || tm4 < MV) {
        float4 bv = make_float4(0.f, 0.f, 0.f, 0.f);
        if (bias) bv = *reinterpret_cast<const float4*>(bias + (size_t)mb * biasmb + tm4);
#pragma unroll
        for (int a = 0; a < 4; a++) {
            int n = n0 + tn4 + a;
            if (n < NN) {
                float4 v;
                if (ACT == 1) {
                    v.x = tanhf(fmaxf(0.25f * acc[a][0] + bv.x, 0.f));
                    v.y = tanhf(fmaxf(0.25f * acc[a][1] + bv.y, 0.f));
                    v.z = tanhf(fmaxf(0.25f * acc[a][2] + bv.z, 0.f));
                    v.w = tanhf(fmaxf(0.25f * acc[a][3] + bv.w, 0.f));
                } else {
                    v = make_float4(acc[a][0] + bv.x, acc[a][1] + bv.y,
                                    acc[a][2] + bv.z, acc[a][3] + bv.w);
                }
                *reinterpret_cast<float4*>(Y + (size_t)mb * ymb + (size_t)n * ldY + tm4) = v;
            }
        }
    }
}

// ===== aggregate 2 + fused alds2: 8 edge-groups x 8 lanes; x3 stride 64; alds epilogue =====
__global__ __launch_bounds__(256) void k_agg2(const int* __restrict__ rp,
                                              const int* __restrict__ srcs2,
                                              const float* __restrict__ y,
                                              const float* __restrict__ bias,
                                              const float* __restrict__ U2p,
                                              float* __restrict__ x3,
                                              float* __restrict__ alds) {
    __shared__ float sh_inv[4][8];
    int wid = threadIdx.x >> 6, lane = threadIdx.x & 63;
    int n = blockIdx.x * 4 + wid;
    int rpv = (lane <= 8) ? rp[n * RR + lane] : 0;
    int nxt = __shfl(rpv, (lane + 1) & 63);
    if (lane < 8) sh_inv[wid][lane] = 1.f / (float)((nxt - rpv) > 0 ? (nxt - rpv) : 1);
    int q = lane & 7;
    int beg = rp[n * RR], end = rp[n * RR + RR];
    float4 acc = make_float4(0.f, 0.f, 0.f, 0.f);
    int k = beg + (lane >> 3);
    for (; k + 8 < end; k += 16) {
        int key0 = srcs2[k], key1 = srcs2[k + 8];
        int s0 = key0 >> 3, s1 = key1 >> 3;
        int g0 = key0 & 7, g1 = key1 & 7;
        float e0 = sh_inv[wid][g0], e1 = sh_inv[wid][g1];
        float4 v0 = *(const float4*)(y + ((size_t)(g0 >> 1) * NN + s0) * 64 + (g0 & 1) * 32 + q * 4);
        float4 v1 = *(const float4*)(y + ((size_t)(g1 >> 1) * NN + s1) * 64 + (g1 & 1) * 32 + q * 4);
        fmacc(acc, v0, e0);
        fmacc(acc, v1, e1);
    }
    if (k < end) {
        int key0 = srcs2[k];
        int s0 = key0 >> 3;
        int g0 = key0 & 7;
        float4 v0 = *(const float4*)(y + ((size_t)(g0 >> 1) * NN + s0) * 64 + (g0 & 1) * 32 + q * 4);
        fmacc(acc, v0, sh_inv[wid][g0]);
    }
    red4(acc, 8);
    red4(acc, 16);
    red4(acc, 32);
    if (lane < 8) {
        float4 prev = *(const float4*)(x3 + (size_t)n * 64 + q * 4);
        float4 b = *(const float4*)(bias + q * 4);
        float4 v;
        v.x = fmaxf(prev.x + acc.x + b.x, 0.f);
        v.y = fmaxf(prev.y + acc.y + b.y, 0.f);
        v.z = fmaxf(prev.z + acc.z + b.z, 0.f);
        v.w = fmaxf(prev.w + acc.w + b.w, 0.f);
        *(float4*)(x3 + (size_t)n * 64 + q * 4) = v;
        // fused alds2: al[j] = sum_c x3[n][c] * U2p[c*64+j], c = q*4..q*4+3 per lane
        float al[8];
#pragma unroll
        for (int j = 0; j < 8; j++) {
            al[j] = fmaf(v.x, U2p[(q * 4 + 0) * 64 + j],
                    fmaf(v.y, U2p[(q * 4 + 1) * 64 + j],
                    fmaf(v.z, U2p[(q * 4 + 2) * 64 + j],
                         v.w * U2p[(q * 4 + 3) * 64 + j])));
        }
#pragma unroll
        for (int m = 1; m < 8; m <<= 1) {
#pragma unroll
            for (int j = 0; j < 8; j++) al[j] += __shfl_xor(al[j], m);
        }
        alds[n * 8 + q] = al[q];
    }
}

// ===== fused GAT aggregation in input space; alds[n][8] = (als[0..3], ald[0..3]) =====
template <int F, int LDX = F>
__global__ __launch_bounds__(256) void k_gatx(const int* __restrict__ rp,
                                              const int* __restrict__ srcs2,
                                              const float* __restrict__ alds,
                                              const float* __restrict__ X,
                                              float* __restrict__ msg) {
    constexpr int G = F / 4;    // lanes per edge-group (16 or 8)
    constexpr int NG = 64 / G;  // groups per wave (4 or 8)
    int wid = threadIdx.x >> 6, lane = threadIdx.x & 63;
    int n = blockIdx.x * 4 + wid;
    if (n >= NN) return;
    int g = lane / G, q = lane % G;
    float4 ald4 = *(const float4*)(alds + n * 8 + 4);
    float4 acc0 = make_float4(0.f, 0.f, 0.f, 0.f);
    float4 acc1 = acc0, acc2 = acc0, acc3 = acc0;
    float4 z = make_float4(0.f, 0.f, 0.f, 0.f);
    if (g == 0) {  // self loop
        float4 a4 = *(const float4*)(alds + n * 8);
        float4 xv = *(const float4*)(X + (size_t)n * LDX + q * 4);
        float p0 = __expf(leaky(a4.x + ald4.x));
        float p1 = __expf(leaky(a4.y + ald4.y));
        float p2 = __expf(leaky(a4.z + ald4.z));
        float p3 = __expf(leaky(a4.w + ald4.w));
        z = make_float4(p0, p1, p2, p3);
        fmacc(acc0, xv, p0);
        fmacc(acc1, xv, p1);
        fmacc(acc2, xv, p2);
        fmacc(acc3, xv, p3);
    }
    int beg = rp[n * RR], end = rp[n * RR + RR];
    int k = beg + g;
    for (; k + NG < end; k += 2 * NG) {
        int s0 = srcs2[k] >> 3, s1 = srcs2[k + NG] >> 3;
        float4 a0 = *(const float4*)(alds + s0 * 8);
        float4 a1 = *(const float4*)(alds + s1 * 8);
        float4 x0 = *(const float4*)(X + (size_t)s0 * LDX + q * 4);
        float4 x1v = *(const float4*)(X + (size_t)s1 * LDX + q * 4);
        float p00 = __expf(leaky(a0.x + ald4.x)), p01 = __expf(leaky(a0.y + ald4.y));
        float p02 = __expf(leaky(a0.z + ald4.z)), p03 = __expf(leaky(a0.w + ald4.w));
        float p10 = __expf(leaky(a1.x + ald4.x)), p11 = __expf(leaky(a1.y + ald4.y));
        float p12 = __expf(leaky(a1.z + ald4.z)), p13 = __expf(leaky(a1.w + ald4.w));
        z.x += p00 + p10;
        z.y += p01 + p11;
        z.z += p02 + p12;
        z.w += p03 + p13;
        fmacc(acc0, x0, p00);
        fmacc(acc1, x0, p01);
        fmacc(acc2, x0, p02);
        fmacc(acc3, x0, p03);
        fmacc(acc0, x1v, p10);
        fmacc(acc1, x1v, p11);
        fmacc(acc2, x1v, p12);
        fmacc(acc3, x1v, p13);
    }
    if (k < end) {
        int s0 = srcs2[k] >> 3;
        float4 a0 = *(const float4*)(alds + s0 * 8);
        float4 x0 = *(const float4*)(X + (size_t)s0 * LDX + q * 4);
        float p00 = __expf(leaky(a0.x + ald4.x)), p01 = __expf(leaky(a0.y + ald4.y));
        float p02 = __expf(leaky(a0.z + ald4.z)), p03 = __expf(leaky(a0.w + ald4.w));
        z.x += p00;
        z.y += p01;
        z.z += p02;
        z.w += p03;
        fmacc(acc0, x0, p00);
        fmacc(acc1, x0, p01);
        fmacc(acc2, x0, p02);
        fmacc(acc3, x0, p03);
    }
#pragma unroll
    for (int m = G; m < 64; m <<= 1) {
        red4(acc0, m);
        red4(acc1, m);
        red4(acc2, m);
        red4(acc3, m);
        red4(z, m);
    }
    if (g == 0) {
        float4 iz = make_float4(1.f / z.x, 1.f / z.y, 1.f / z.z, 1.f / z.w);
        float* mp = msg + (size_t)n * 4 * F + q * 4;
        *(float4*)(mp + 0 * F) = make_float4(acc0.x * iz.x, acc0.y * iz.x, acc0.z * iz.x, acc0.w * iz.x);
        *(float4*)(mp + 1 * F) = make_float4(acc1.x * iz.y, acc1.y * iz.y, acc1.z * iz.y, acc1.w * iz.y);
        *(float4*)(mp + 2 * F) = make_float4(acc2.x * iz.z, acc2.y * iz.z, acc2.z * iz.z, acc2.w * iz.z);
        *(float4*)(mp + 3 * F) = make_float4(acc3.x * iz.w, acc3.y * iz.w, acc3.z * iz.w, acc3.w * iz.w);
    }
}

extern "C" void kernel_launch(void* const* d_in, const int* in_sizes, int n_in,
                              void* d_out, int out_size, void* d_ws, size_t ws_size,
                              hipStream_t stream) {
    const float* x      = (const float*)d_in[0];
    const int*   ei     = (const int*)d_in[1];
    const int*   et     = (const int*)d_in[2];
    const float* basis1 = (const float*)d_in[3];
    const float* comp1  = (const float*)d_in[4];
    const float* root1  = (const float*)d_in[5];
    const float* brg1   = (const float*)d_in[6];
    const float* wg1    = (const float*)d_in[7];
    const float* asrc1  = (const float*)d_in[8];
    const float* adst1  = (const float*)d_in[9];
    const float* bg1    = (const float*)d_in[10];
    const float* basis2 = (const float*)d_in[11];
    const float* comp2  = (const float*)d_in[12];
    const float* root2  = (const float*)d_in[13];
    const float* brg2   = (const float*)d_in[14];
    const float* wg2    = (const float*)d_in[15];
    const float* asrc2  = (const float*)d_in[16];
    const float* adst2  = (const float*)d_in[17];
    const float* bg2    = (const float*)d_in[18];
    const int* src = ei;
    const int* dst = ei + EE;
    float* out = (float*)d_out;

    // ---- int region ----
    int* wsi = (int*)d_ws;
    size_t ioff = 0;
    auto ialloc = [&](size_t n) { int* p = wsi + ioff; ioff += (n + 3) & ~(size_t)3; return p; };
    int* cnt2 = ialloc(SEGS);  // reused as fill cursors (wo)
    int* rp   = ialloc(SEGS + 1);
    int* bsum = ialloc(2048);
    int* srcs2 = ialloc(EE);
    int* wo = cnt2;
    // ---- float region ----
    float* wsf = (float*)(wsi + ioff);
    size_t total_f = (ws_size - ioff * sizeof(int)) / sizeof(float);
    size_t P_f = (size_t)NN * 320;
    size_t need_f = P_f + (size_t)NN * 128
                  + 40960 + 20480 + 16384 + 8192 + 4096 + 2048
                  + (size_t)NN * 8 + 64;
    if (total_f < need_f) return;  // loud fail: output stays zero
    size_t foff = 0;
    auto falloc = [&](size_t n) { float* p = wsf + foff; foff += (n + 3) & ~(size_t)3; return p; };
    float* P      = falloc(P_f);
    float* x2     = falloc((size_t)NN * 128);
    float* Wcat2e = falloc(40960);           // [128][320]: root2(pad) | W_r pairs
    float* Wb1    = falloc(20480);           // [320][64]: basis1 rows | root1 rows
    float* wg1r   = falloc(16384);
    float* Wstk   = falloc(8192);
    float* U1p    = falloc(4096);
    float* U2p    = falloc(2048);
    float* alds   = falloc((size_t)NN * 8);
    float* Ubuf = P;                  // L1 basis-gather output [n][320]
    float* x1   = x2 + (size_t)NN * 64;  // dead before msg1-gemm overwrites x2 region
    float* msg1 = P;                  // [n][4][64] (U dead after u-gemm)
    float* x3   = P;                  // stride 64, cols 32-63 pad (L3)
    float* ybuf3 = P + (size_t)NN * 64;  // L3 transform out, 4*NN*64
    float* msg2 = P + (size_t)NN * 64;   // [n][4][32] (ybuf3 dead after agg2; disjoint from x3)

    const int EB = (EE + 255) / 256;
    const int NB4 = (NN + 3) / 4;    // NN % 4 == 0 -> exact
    const int NT = (NN + 63) / 64;   // 782 (small gemm tiles)
    const int NT2 = (NN + 127) / 128;       // 391 (big gemm tiles)
    const int NT28 = ((NT2 + 7) / 8) * 8;   // 392: XCD-swizzle rounding

    // ---- CSR build ----
    hipMemsetAsync(cnt2, 0, SEGS * sizeof(int), stream);
    k_count2<<<EB, 256, 0, stream>>>(dst, et, cnt2);
    k_scanA<<<NBLK, 256, 0, stream>>>(cnt2, rp, bsum);
    k_scanB<<<1, 256, 0, stream>>>(bsum);
    k_scanC<<<NBLK, 256, 0, stream>>>(rp, bsum, wo);
    k_fill<<<EB, 256, 0, stream>>>(src, dst, et, wo, srcs2);
    k_prep<<<(92160 + 255) / 256, 256, 0, stream>>>(
        wg1, wg2, root1, root2, basis1, basis2, comp2, asrc1, adst1, asrc2, adst2,
        Wcat2e, wg1r, Wstk, U1p, U2p, Wb1);

    // ---- layer 1: RGCN(64->64)+relu via basis-space gather + one K=320 GEMM ----
    k_gagg1<<<NB4, 256, 0, stream>>>(rp, srcs2, comp1, x, Ubuf);
    k_gemm128<320, 64, 2><<<dim3(NT2, 1), 256, 0, stream>>>(Ubuf, 320, 0, Wb1, 64, 0,
                                                            x1, 64, 0, brg1, 0, NT2, 0);

    // ---- layer 2: GAT(64 -> 4x32 concat), aggregated in input space ----
    k_gemm64<64, 8><<<dim3(NT, 1), 256, 0, stream>>>(x1, 64, 0, U1p, 64, 0, alds, 8, 0,
                                                     nullptr, 0, NT, 0);
    k_gatx<64><<<NB4, 256, 0, stream>>>(rp, srcs2, alds, x1, msg1);
    k_gemm128<64, 32><<<dim3(NT2, 4), 256, 0, stream>>>(msg1, 256, 64, wg1r, 64, 4096,
                                                        x2, 128, 32, bg1, 32, NT2, 0);

    // ---- layer 3: RGCN(128->32)+relu; XCD-swizzled fused transform (root + 8 rel) ----
    k_gemm128<128><<<NT28 * 5, 256, 0, stream>>>(x2, 128, 0, Wcat2e, 320, 64,
                                                 P, 64, (size_t)NN * 64, nullptr, 0, NT2, 5);
    k_agg2<<<NB4, 256, 0, stream>>>(rp, srcs2, ybuf3, brg2, U2p, x3, alds);

    // ---- layer 4: GAT(32 -> 4x16, mean heads) + relu + tanh (alds fused into agg2) ----
    k_gatx<32, 64><<<NB4, 256, 0, stream>>>(rp, srcs2, alds, x3, msg2);
    k_gemm64<128, 16, 1><<<dim3(NT, 1), 256, 0, stream>>>(msg2, 128, 0, Wstk, 64, 0,
                                                          out, 16, 0, bg2, 0, NT, 0);
}